// Round 3
// baseline (787.403 us; speedup 1.0000x reference)
//
#include <hip/hip_runtime.h>
#include <hip/hip_bf16.h>
#include <math.h>

// Problem constants (from reference): D=128, H=4, HD=32, K=1.0
// Derived at runtime: N = in_sizes[0]/129, E = in_sizes[1]/2.
//
// Pipeline:
//  P0  prep:      build WT[129][384] (qkv weights transposed, channel-major),
//                 bias[384], WoT[129][128]
//  K1  qkv_gemm:  space parts of q,k,v -> [N][H][36] padded rows (space 0..31),
//                 FUSED epilogue: time=sqrt(|space|^2+1) at slot 32 (NEGATED for k),
//                 zero at slot 33 (8-lane shfl reduction; block owns 2 whole heads)
//  K2a count:     deg[dst]++
//  K2b-d scan:    hierarchical exclusive scan -> offsets (CSR)
//  K2e fill:      srcs grouped by dst, pre-scaled by ROWF
//  K3  attn:      per (node,head) x 2-way edge split: online-softmax Lorentz aggregation
//                 in registers (packed f32 math), shfl merge. Softmax denominator skipped:
//                 out = agg/sqrt(|<agg,agg>|) is scale-invariant.
//  K4  final:     out = hyp_linear(concat(time,space), Wo, bo)

#define HDIM 36          // padded per-head row: space[0..31], time[32], zero[33], pad[34..35]
#define ROWF 144         // 4 heads * 36

typedef float f2 __attribute__((ext_vector_type(2)));

__global__ void prep_kernel(const float* __restrict__ Wq, const float* __restrict__ bq,
                            const float* __restrict__ Wk, const float* __restrict__ bk,
                            const float* __restrict__ Wv, const float* __restrict__ bv,
                            const float* __restrict__ Wo,
                            float* __restrict__ WT, float* __restrict__ bias,
                            float* __restrict__ WoT) {
    const int T1 = 129 * 384;
    const int T2 = T1 + 384;
    const int T3 = T2 + 129 * 128;
    for (int i = blockIdx.x * blockDim.x + threadIdx.x; i < T3; i += gridDim.x * blockDim.x) {
        if (i < T1) {
            int k = i / 384, o = i % 384;
            const float* W = (o < 128) ? Wq : (o < 256 ? Wk : Wv);
            int r = o & 127;
            WT[i] = W[(size_t)r * 129 + k];
        } else if (i < T2) {
            int o = i - T1;
            const float* b = (o < 128) ? bq : (o < 256 ? bk : bv);
            bias[o] = b[o & 127];
        } else {
            int j = i - T2;
            int k = j >> 7, o = j & 127;
            WoT[j] = Wo[(size_t)o * 129 + k];
        }
    }
}

// ---- K1: C[n][ch] = sum_k x[n][k] * WT[k][ch], ch in [0,384) -> q/k/v space+time ----
// Block computes a 64-node x 64-channel tile; 64 channels = exactly 2 complete heads
// of one tensor (q, k, or v), so the hyperboloid time coordinate is computed in the
// epilogue via an 8-lane shuffle reduction (lanes tx&7 hold the head's 32 dims).
__global__ __launch_bounds__(256) void qkv_gemm(const float* __restrict__ x,
                                                const float* __restrict__ WT,
                                                const float* __restrict__ bias,
                                                float* __restrict__ qh, float* __restrict__ kh,
                                                float* __restrict__ vh, int Nn) {
    __shared__ __align__(16) float xs[16][68];
    __shared__ __align__(16) float ws[16][64];
    int tid = threadIdx.x;
    int tx = tid & 15, ty = tid >> 4;
    int nbase = blockIdx.x * 64;
    int cbase = blockIdx.y * 64;
    float acc[4][4];
#pragma unroll
    for (int i = 0; i < 4; i++)
#pragma unroll
        for (int j = 0; j < 4; j++) acc[i][j] = 0.f;

    for (int k0 = 0; k0 < 129; k0 += 16) {
#pragma unroll
        for (int i = tid; i < 64 * 16; i += 256) {
            int nl = i >> 4, kk = i & 15;
            int n = nbase + nl, k = k0 + kk;
            xs[kk][nl] = (n < Nn && k < 129) ? x[(size_t)n * 129 + k] : 0.f;
        }
#pragma unroll
        for (int i = tid; i < 16 * 64; i += 256) {
            int kk = i >> 6, c = i & 63;
            int k = k0 + kk;
            ws[kk][c] = (k < 129) ? WT[(size_t)k * 384 + cbase + c] : 0.f;
        }
        __syncthreads();
#pragma unroll
        for (int kk = 0; kk < 16; kk++) {
            float4 a = *(const float4*)&xs[kk][ty * 4];
            float4 b = *(const float4*)&ws[kk][tx * 4];
            float av[4] = {a.x, a.y, a.z, a.w};
            float bw[4] = {b.x, b.y, b.z, b.w};
#pragma unroll
            for (int i = 0; i < 4; i++)
#pragma unroll
                for (int j = 0; j < 4; j++) acc[i][j] += av[i] * bw[j];
        }
        __syncthreads();
    }
    // epilogue: 4 contiguous channels per thread -> float4 stores + fused time coord
    int ch0 = cbase + tx * 4;
    float4 bb = *(const float4*)&bias[ch0];
    int t = cbase >> 7;                     // 0=q, 1=k, 2=v (uniform per block)
    int r = ch0 & 127, hh = r >> 5, jj0 = r & 31;
    float* dstp = (t == 0) ? qh : (t == 1 ? kh : vh);
    float tsign = (t == 1) ? -1.f : 1.f;    // k time stored negated
#pragma unroll
    for (int i = 0; i < 4; i++) {
        int n = nbase + ty * 4 + i;
        float4 o;
        o.x = acc[i][0] + bb.x;
        o.y = acc[i][1] + bb.y;
        o.z = acc[i][2] + bb.z;
        o.w = acc[i][3] + bb.w;
        if (n < Nn) *(float4*)&dstp[(size_t)n * ROWF + hh * HDIM + jj0] = o;
        // sum of squares over this head's 32 dims: 8 lanes (tx&7) x 4 ch each
        float s = o.x * o.x + o.y * o.y + o.z * o.z + o.w * o.w;
        s += __shfl_xor(s, 1);
        s += __shfl_xor(s, 2);
        s += __shfl_xor(s, 4);
        if ((tx & 7) == 0 && n < Nn) {
            f2 tw;
            tw.x = tsign * sqrtf(s + 1.0f);
            tw.y = 0.f;
            *(f2*)&dstp[(size_t)n * ROWF + hh * HDIM + 32] = tw;
        }
    }
}

__global__ void count_kernel(const int* __restrict__ ei, int* __restrict__ deg, int E) {
    int e = blockIdx.x * blockDim.x + threadIdx.x;
    if (e < E) atomicAdd(&deg[ei[E + e]], 1);
}

// ---- hierarchical exclusive scan (N <= 256*256) ----
__global__ __launch_bounds__(256) void scan_blocks(const int* __restrict__ deg,
                                                   int* __restrict__ offsets,
                                                   int* __restrict__ partials, int n) {
    __shared__ int wsum[4];
    int tid = threadIdx.x;
    int idx = blockIdx.x * 256 + tid;
    int lane = tid & 63, wid = tid >> 6;
    int v = (idx < n) ? deg[idx] : 0;
    int x = v;
#pragma unroll
    for (int d = 1; d < 64; d <<= 1) {
        int y = __shfl_up(x, d, 64);
        if (lane >= d) x += y;
    }
    if (lane == 63) wsum[wid] = x;
    __syncthreads();
    if (tid == 0) {
        int s = 0;
#pragma unroll
        for (int i = 0; i < 4; i++) { int tv = wsum[i]; wsum[i] = s; s += tv; }
    }
    __syncthreads();
    int excl = wsum[wid] + x - v;
    if (idx < n) offsets[idx] = excl;
    if (tid == 255) partials[blockIdx.x] = excl + v;
}

__global__ __launch_bounds__(256) void scan_partials(int* __restrict__ partials,
                                                     int* __restrict__ total_out, int nb) {
    __shared__ int wsum[4];
    int tid = threadIdx.x;
    int lane = tid & 63, wid = tid >> 6;
    int v = (tid < nb) ? partials[tid] : 0;
    int x = v;
#pragma unroll
    for (int d = 1; d < 64; d <<= 1) {
        int y = __shfl_up(x, d, 64);
        if (lane >= d) x += y;
    }
    if (lane == 63) wsum[wid] = x;
    __syncthreads();
    if (tid == 0) {
        int s = 0;
#pragma unroll
        for (int i = 0; i < 4; i++) { int tv = wsum[i]; wsum[i] = s; s += tv; }
    }
    __syncthreads();
    int excl = wsum[wid] + x - v;
    if (tid < nb) partials[tid] = excl;
    if (tid == 255) *total_out = excl + v;
}

__global__ void scan_add(int* __restrict__ offsets, const int* __restrict__ partials, int n) {
    int idx = blockIdx.x * blockDim.x + threadIdx.x;
    if (idx < n) offsets[idx] += partials[blockIdx.x];
}

__global__ void fill_kernel(const int* __restrict__ ei, const int* __restrict__ offsets,
                            int* __restrict__ cursor, int* __restrict__ srcs, int E) {
    int e = blockIdx.x * blockDim.x + threadIdx.x;
    if (e < E) {
        int src = ei[e];
        int dst = ei[E + e];
        int pos = atomicAdd(&cursor[dst], 1);
        srcs[offsets[dst] + pos] = src * ROWF;   // pre-scaled row offset
    }
}

// ---- K3: per (node, head) x 2 edge-split online-softmax Lorentz aggregation ----
// lane layout: gid = n*8 + t*4 + h  (4 heads contiguous -> adjacent lanes read one row;
// t=0/1 handle interleaved halves of the edge list, merged via shfl_xor(.,4))
__global__ __launch_bounds__(256) void attn_kernel(const float* __restrict__ qh,
                                                   const float* __restrict__ kh,
                                                   const float* __restrict__ vh,
                                                   const int* __restrict__ offsets,
                                                   const int* __restrict__ soff,
                                                   float* __restrict__ mid, int Nn) {
    int gid = blockIdx.x * blockDim.x + threadIdx.x;
    if (gid >= Nn * 8) return;
    int h = gid & 3, t = (gid >> 2) & 1, n = gid >> 3;

    const float* qrow = qh + (size_t)n * ROWF + h * HDIM;
    float qs[34];
#pragma unroll
    for (int i = 0; i < 8; i++) *(float4*)&qs[i * 4] = *(const float4*)&qrow[i * 4];
    *(f2*)&qs[32] = *(const f2*)&qrow[32];

    int r0 = offsets[n], r1 = offsets[n + 1];
    float m = -INFINITY;
    float acc[34];
#pragma unroll
    for (int i = 0; i < 34; i++) acc[i] = 0.f;

    int e = r0 + t;
    int off = (e < r1) ? soff[e] : 0;
    for (; e < r1; e += 2) {
        int offn = (e + 2 < r1) ? soff[e + 2] : 0;   // prefetch next row offset
        const float* krow = kh + off + h * HDIM;
        const float* vrow = vh + off + h * HDIM;
        float ks[34], vs[34];
#pragma unroll
        for (int i = 0; i < 8; i++) *(float4*)&ks[i * 4] = *(const float4*)&krow[i * 4];
        *(f2*)&ks[32] = *(const f2*)&krow[32];
#pragma unroll
        for (int i = 0; i < 8; i++) *(float4*)&vs[i * 4] = *(const float4*)&vrow[i * 4];
        *(f2*)&vs[32] = *(const f2*)&vrow[32];

        // 34-dim packed dot == <q,k> - q_t*k_t  (k time stored negated, pads zero)
        f2 d2 = {0.f, 0.f};
#pragma unroll
        for (int j = 0; j < 17; j++) d2 += ((const f2*)qs)[j] * ((const f2*)ks)[j];
        float s = (1.f + d2.x + d2.y) * 0.35355339059327373f;  // (2+2c)/sqrt(32)

        float mn = fmaxf(m, s);
        float cor = __expf(m - mn);   // 0 on first edge (m=-inf)
        float p = __expf(s - mn);
        m = mn;
#pragma unroll
        for (int j = 0; j < 17; j++) {
            f2 a = ((f2*)acc)[j];
            ((f2*)acc)[j] = a * cor + ((const f2*)vs)[j] * p;
        }
        off = offn;
    }

    // merge the two edge-halves (partner lane = lane ^ 4)
    float mo = __shfl_xor(m, 4);
    float M = fmaxf(m, mo);
    float scale = (m > -INFINITY) ? __expf(m - M) : 0.f;  // guard empty-half NaN
#pragma unroll
    for (int i = 0; i < 33; i++) {
        float a = acc[i] * scale;
        acc[i] = a + __shfl_xor(a, 4);
    }

    // out = acc / sqrt(clip(|<acc,acc>_L|, 1e-8))  (softmax denom cancels)
    float ss = 0.f;
#pragma unroll
    for (int j = 0; j < 32; j++) ss += acc[j] * acc[j];
    float c = ss - acc[32] * acc[32];
    float d = sqrtf(fmaxf(fabsf(c), 1e-8f));
    float inv = 1.0f / d;

    // split store: t=0 writes floats 0..15, t=1 writes 16..31 (static indices only)
    float* orow = mid + (size_t)n * 128 + h * 32;
    if (t == 0) {
#pragma unroll
        for (int i = 0; i < 4; i++) {
            float4 o4;
            o4.x = acc[i * 4 + 0] * inv;
            o4.y = acc[i * 4 + 1] * inv;
            o4.z = acc[i * 4 + 2] * inv;
            o4.w = acc[i * 4 + 3] * inv;
            *(float4*)&orow[i * 4] = o4;
        }
    } else {
#pragma unroll
        for (int i = 0; i < 4; i++) {
            float4 o4;
            o4.x = acc[16 + i * 4 + 0] * inv;
            o4.y = acc[16 + i * 4 + 1] * inv;
            o4.z = acc[16 + i * 4 + 2] * inv;
            o4.w = acc[16 + i * 4 + 3] * inv;
            *(float4*)&orow[16 + i * 4] = o4;
        }
    }
}

// ---- K4: final hyperbolic linear: 32 nodes/block, 128 threads (one per out-dim) ----
__global__ __launch_bounds__(128) void final_linear(const float* __restrict__ mid,
                                                    const float* __restrict__ WoT,
                                                    const float* __restrict__ bo,
                                                    float* __restrict__ out, int Nn) {
    __shared__ __align__(16) float xl[32][132];
    int tid = threadIdx.x;
    int nb = blockIdx.x * 32;
#pragma unroll
    for (int i = 0; i < 32; i++) {
        int n = nb + i;
        xl[i][1 + tid] = (n < Nn) ? mid[(size_t)n * 128 + tid] : 0.f;
    }
    __syncthreads();
    int nl = tid >> 2, sub = tid & 3;
    {
        float s = 0.f;
#pragma unroll
        for (int j = 0; j < 32; j++) {
            float v = xl[nl][1 + sub * 32 + j];
            s += v * v;
        }
        s += __shfl_xor(s, 1);
        s += __shfl_xor(s, 2);
        if (sub == 0) xl[nl][0] = sqrtf(s + 1.0f);
    }
    __syncthreads();

    float bv = bo[tid];
    float acc[32];
#pragma unroll
    for (int i = 0; i < 32; i++) acc[i] = bv;

    for (int k = 0; k < 128; k += 4) {
        float w0 = WoT[(size_t)(k + 0) * 128 + tid];
        float w1 = WoT[(size_t)(k + 1) * 128 + tid];
        float w2 = WoT[(size_t)(k + 2) * 128 + tid];
        float w3 = WoT[(size_t)(k + 3) * 128 + tid];
#pragma unroll
        for (int i = 0; i < 32; i++) {
            float4 xv = *(const float4*)&xl[i][k];   // broadcast reads
            acc[i] += w0 * xv.x + w1 * xv.y + w2 * xv.z + w3 * xv.w;
        }
    }
    {
        float w = WoT[(size_t)128 * 128 + tid];
#pragma unroll
        for (int i = 0; i < 32; i++) acc[i] += w * xl[i][128];
    }
    __syncthreads();
#pragma unroll
    for (int i = 0; i < 32; i++) {
        int n = nb + i;
        if (n < Nn) out[(size_t)n * 129 + 1 + tid] = acc[i];
        xl[i][tid] = acc[i] * acc[i];
    }
    __syncthreads();
    {
        float s = 0.f;
#pragma unroll
        for (int j = 0; j < 32; j++) s += xl[nl][sub * 32 + j];
        s += __shfl_xor(s, 1);
        s += __shfl_xor(s, 2);
        if (sub == 0 && (nb + nl) < Nn) out[(size_t)(nb + nl) * 129] = sqrtf(s + 1.0f);
    }
}

// legacy single-block scan fallback (only used if N > 65536)
__global__ __launch_bounds__(1024) void scan_kernel(const int* __restrict__ deg,
                                                    int* __restrict__ offsets, int n) {
    __shared__ int wsum[16];
    __shared__ int carry_s;
    int tid = threadIdx.x;
    int lane = tid & 63, wid = tid >> 6;
    if (tid == 0) carry_s = 0;
    __syncthreads();
    for (int base = 0; base < n; base += 1024) {
        int idx = base + tid;
        int v = (idx < n) ? deg[idx] : 0;
        int x = v;
#pragma unroll
        for (int d = 1; d < 64; d <<= 1) {
            int y = __shfl_up(x, d, 64);
            if (lane >= d) x += y;
        }
        if (lane == 63) wsum[wid] = x;
        __syncthreads();
        if (wid == 0) {
            int s = (lane < 16) ? wsum[lane] : 0;
#pragma unroll
            for (int d = 1; d < 16; d <<= 1) {
                int y = __shfl_up(s, d, 64);
                if (lane >= d) s += y;
            }
            if (lane < 16) wsum[lane] = s;
        }
        __syncthreads();
        int waveoff = (wid > 0) ? wsum[wid - 1] : 0;
        int excl = carry_s + waveoff + x - v;
        if (idx < n) offsets[idx] = excl;
        __syncthreads();
        if (tid == 0) carry_s += wsum[15];
        __syncthreads();
    }
    if (tid == 0) offsets[n] = carry_s;
}

extern "C" void kernel_launch(void* const* d_in, const int* in_sizes, int n_in,
                              void* d_out, int out_size, void* d_ws, size_t ws_size,
                              hipStream_t stream) {
    const float* x  = (const float*)d_in[0];
    const int*   ei = (const int*)d_in[1];
    const float* Wq = (const float*)d_in[2];
    const float* bq = (const float*)d_in[3];
    const float* Wk = (const float*)d_in[4];
    const float* bk = (const float*)d_in[5];
    const float* Wv = (const float*)d_in[6];
    const float* bv = (const float*)d_in[7];
    const float* Wo = (const float*)d_in[8];
    const float* bo = (const float*)d_in[9];
    float* out = (float*)d_out;

    const int N = in_sizes[0] / 129;
    const int E = in_sizes[1] / 2;

    // workspace layout (256B-aligned bump allocator)
    char* w = (char*)d_ws;
    size_t off = 0;
    auto alloc = [&](size_t bytes) {
        void* p = w + off;
        off += (bytes + 255) & ~(size_t)255;
        return p;
    };
    float* qh       = (float*)alloc((size_t)N * ROWF * 4);
    float* kh       = (float*)alloc((size_t)N * ROWF * 4);
    float* vh       = (float*)alloc((size_t)N * ROWF * 4);
    float* mid      = (float*)alloc((size_t)N * 128 * 4);
    float* WT       = (float*)alloc(129 * 384 * 4);
    float* bias     = (float*)alloc(384 * 4);
    float* WoT      = (float*)alloc(129 * 128 * 4);
    int*   offsets  = (int*)alloc((size_t)(N + 1) * 4);
    int*   degcur   = (int*)alloc((size_t)2 * N * 4);  // deg[N] + cursor[N]
    int*   deg      = degcur;
    int*   cursor   = degcur + N;
    int*   partials = (int*)alloc(256 * 4);
    int*   srcs     = (int*)alloc((size_t)E * 4);

    hipMemsetAsync(degcur, 0, (size_t)2 * N * 4, stream);

    prep_kernel<<<260, 256, 0, stream>>>(Wq, bq, Wk, bk, Wv, bv, Wo, WT, bias, WoT);

    dim3 g1((N + 63) / 64, 6);
    qkv_gemm<<<g1, 256, 0, stream>>>(x, WT, bias, qh, kh, vh, N);

    count_kernel<<<(E + 255) / 256, 256, 0, stream>>>(ei, deg, E);

    int nb = (N + 255) / 256;
    if (nb <= 256) {
        scan_blocks<<<nb, 256, 0, stream>>>(deg, offsets, partials, N);
        scan_partials<<<1, 256, 0, stream>>>(partials, offsets + N, nb);
        scan_add<<<nb, 256, 0, stream>>>(offsets, partials, N);
    } else {
        scan_kernel<<<1, 1024, 0, stream>>>(deg, offsets, N);
    }

    fill_kernel<<<(E + 255) / 256, 256, 0, stream>>>(ei, offsets, cursor, srcs, E);

    attn_kernel<<<(N * 8 + 255) / 256, 256, 0, stream>>>(qh, kh, vh, offsets, srcs, mid, N);

    final_linear<<<(N + 31) / 32, 128, 0, stream>>>(mid, WoT, bo, out, N);
}

// Round 4
// 547.779 us; speedup vs baseline: 1.4374x; 1.4374x over previous
//
#include <hip/hip_runtime.h>
#include <hip/hip_bf16.h>
#include <math.h>

// Problem constants (from reference): D=128, H=4, HD=32, K=1.0
// Derived at runtime: N = in_sizes[0]/129, E = in_sizes[1]/2.
//
// Pipeline:
//  P0  prep:      build WT[129][384] (qkv weights transposed, channel-major),
//                 bias[384], WoT[129][128]
//  K1  qkv_gemm:  space parts of q,k,v -> dense [N][128] fp32 (head h = cols h*32..h*32+31)
//                 (time coords NOT stored -- recomputed in attn; rows cache-line aligned)
//  K2a count:     deg[dst]++
//  K2b-d scan:    hierarchical exclusive scan -> offsets (CSR)
//  K2e fill:      srcs grouped by dst, pre-scaled by 128
//  K3  attn:      per (node,head) x 4-way edge split: exp-weighted Lorentz aggregation
//                 in registers, shfl merge. No max subtraction needed: <q,k>_L <= -1 on the
//                 hyperboloid => score <= 0 => exp in (0,1]. Softmax denominator skipped:
//                 out = agg/sqrt(|<agg,agg>|) is scale-invariant.
//  K4  final:     out = hyp_linear(concat(time,space), Wo, bo)

typedef float f2 __attribute__((ext_vector_type(2)));

__global__ void prep_kernel(const float* __restrict__ Wq, const float* __restrict__ bq,
                            const float* __restrict__ Wk, const float* __restrict__ bk,
                            const float* __restrict__ Wv, const float* __restrict__ bv,
                            const float* __restrict__ Wo,
                            float* __restrict__ WT, float* __restrict__ bias,
                            float* __restrict__ WoT) {
    const int T1 = 129 * 384;
    const int T2 = T1 + 384;
    const int T3 = T2 + 129 * 128;
    for (int i = blockIdx.x * blockDim.x + threadIdx.x; i < T3; i += gridDim.x * blockDim.x) {
        if (i < T1) {
            int k = i / 384, o = i % 384;
            const float* W = (o < 128) ? Wq : (o < 256 ? Wk : Wv);
            int r = o & 127;
            WT[i] = W[(size_t)r * 129 + k];
        } else if (i < T2) {
            int o = i - T1;
            const float* b = (o < 128) ? bq : (o < 256 ? bk : bv);
            bias[o] = b[o & 127];
        } else {
            int j = i - T2;
            int k = j >> 7, o = j & 127;
            WoT[j] = Wo[(size_t)o * 129 + k];
        }
    }
}

// ---- K1: C[n][ch] = sum_k x[n][k] * WT[k][ch], ch in [0,384) -> q/k/v [N][128] ----
__global__ __launch_bounds__(256) void qkv_gemm(const float* __restrict__ x,
                                                const float* __restrict__ WT,
                                                const float* __restrict__ bias,
                                                float* __restrict__ qh, float* __restrict__ kh,
                                                float* __restrict__ vh, int Nn) {
    __shared__ __align__(16) float xs[16][68];
    __shared__ __align__(16) float ws[16][64];
    int tid = threadIdx.x;
    int tx = tid & 15, ty = tid >> 4;
    int nbase = blockIdx.x * 64;
    int cbase = blockIdx.y * 64;
    float acc[4][4];
#pragma unroll
    for (int i = 0; i < 4; i++)
#pragma unroll
        for (int j = 0; j < 4; j++) acc[i][j] = 0.f;

    for (int k0 = 0; k0 < 129; k0 += 16) {
#pragma unroll
        for (int i = tid; i < 64 * 16; i += 256) {
            int nl = i >> 4, kk = i & 15;
            int n = nbase + nl, k = k0 + kk;
            xs[kk][nl] = (n < Nn && k < 129) ? x[(size_t)n * 129 + k] : 0.f;
        }
#pragma unroll
        for (int i = tid; i < 16 * 64; i += 256) {
            int kk = i >> 6, c = i & 63;
            int k = k0 + kk;
            ws[kk][c] = (k < 129) ? WT[(size_t)k * 384 + cbase + c] : 0.f;
        }
        __syncthreads();
#pragma unroll
        for (int kk = 0; kk < 16; kk++) {
            float4 a = *(const float4*)&xs[kk][ty * 4];
            float4 b = *(const float4*)&ws[kk][tx * 4];
            float av[4] = {a.x, a.y, a.z, a.w};
            float bw[4] = {b.x, b.y, b.z, b.w};
#pragma unroll
            for (int i = 0; i < 4; i++)
#pragma unroll
                for (int j = 0; j < 4; j++) acc[i][j] += av[i] * bw[j];
        }
        __syncthreads();
    }
    // epilogue: 4 contiguous channels per thread -> plain [N][128] float4 stores
    int ch0 = cbase + tx * 4;
    float4 bb = *(const float4*)&bias[ch0];
    int t = cbase >> 7;                     // 0=q, 1=k, 2=v (uniform per block)
    int r = ch0 & 127;
    float* dstp = (t == 0) ? qh : (t == 1 ? kh : vh);
#pragma unroll
    for (int i = 0; i < 4; i++) {
        int n = nbase + ty * 4 + i;
        if (n < Nn) {
            float4 o;
            o.x = acc[i][0] + bb.x;
            o.y = acc[i][1] + bb.y;
            o.z = acc[i][2] + bb.z;
            o.w = acc[i][3] + bb.w;
            *(float4*)&dstp[(size_t)n * 128 + r] = o;
        }
    }
}

__global__ void count_kernel(const int* __restrict__ ei, int* __restrict__ deg, int E) {
    int e = blockIdx.x * blockDim.x + threadIdx.x;
    if (e < E) atomicAdd(&deg[ei[E + e]], 1);
}

// ---- hierarchical exclusive scan (N <= 256*256) ----
__global__ __launch_bounds__(256) void scan_blocks(const int* __restrict__ deg,
                                                   int* __restrict__ offsets,
                                                   int* __restrict__ partials, int n) {
    __shared__ int wsum[4];
    int tid = threadIdx.x;
    int idx = blockIdx.x * 256 + tid;
    int lane = tid & 63, wid = tid >> 6;
    int v = (idx < n) ? deg[idx] : 0;
    int x = v;
#pragma unroll
    for (int d = 1; d < 64; d <<= 1) {
        int y = __shfl_up(x, d, 64);
        if (lane >= d) x += y;
    }
    if (lane == 63) wsum[wid] = x;
    __syncthreads();
    if (tid == 0) {
        int s = 0;
#pragma unroll
        for (int i = 0; i < 4; i++) { int tv = wsum[i]; wsum[i] = s; s += tv; }
    }
    __syncthreads();
    int excl = wsum[wid] + x - v;
    if (idx < n) offsets[idx] = excl;
    if (tid == 255) partials[blockIdx.x] = excl + v;
}

__global__ __launch_bounds__(256) void scan_partials(int* __restrict__ partials,
                                                     int* __restrict__ total_out, int nb) {
    __shared__ int wsum[4];
    int tid = threadIdx.x;
    int lane = tid & 63, wid = tid >> 6;
    int v = (tid < nb) ? partials[tid] : 0;
    int x = v;
#pragma unroll
    for (int d = 1; d < 64; d <<= 1) {
        int y = __shfl_up(x, d, 64);
        if (lane >= d) x += y;
    }
    if (lane == 63) wsum[wid] = x;
    __syncthreads();
    if (tid == 0) {
        int s = 0;
#pragma unroll
        for (int i = 0; i < 4; i++) { int tv = wsum[i]; wsum[i] = s; s += tv; }
    }
    __syncthreads();
    int excl = wsum[wid] + x - v;
    if (tid < nb) partials[tid] = excl;
    if (tid == 255) *total_out = excl + v;
}

__global__ void scan_add(int* __restrict__ offsets, const int* __restrict__ partials, int n) {
    int idx = blockIdx.x * blockDim.x + threadIdx.x;
    if (idx < n) offsets[idx] += partials[blockIdx.x];
}

__global__ void fill_kernel(const int* __restrict__ ei, const int* __restrict__ offsets,
                            int* __restrict__ cursor, int* __restrict__ srcs, int E) {
    int e = blockIdx.x * blockDim.x + threadIdx.x;
    if (e < E) {
        int src = ei[e];
        int dst = ei[E + e];
        int pos = atomicAdd(&cursor[dst], 1);
        srcs[offsets[dst] + pos] = src * 128;   // pre-scaled row offset
    }
}

// ---- K3: per (node, head) x 4-way edge split, exp-weighted Lorentz aggregation ----
// lane layout: gid = n*16 + t*4 + h  (4 h-lanes of one (n,t) read one contiguous 512B row;
// t=0..3 handle interleaved quarters of the edge list, merged via shfl_xor 4 & 8)
__global__ __launch_bounds__(256) void attn_kernel(const float* __restrict__ qh,
                                                   const float* __restrict__ kh,
                                                   const float* __restrict__ vh,
                                                   const int* __restrict__ offsets,
                                                   const int* __restrict__ soff,
                                                   float* __restrict__ mid, int Nn) {
    int gid = blockIdx.x * blockDim.x + threadIdx.x;
    if (gid >= Nn * 16) return;
    int h = gid & 3, t = (gid >> 2) & 3, n = gid >> 4;

    const float* qrow = qh + (size_t)n * 128 + h * 32;
    float qs[32] __attribute__((aligned(16)));
#pragma unroll
    for (int i = 0; i < 8; i++) *(float4*)&qs[i * 4] = *(const float4*)&qrow[i * 4];
    f2 q2 = {0.f, 0.f};
#pragma unroll
    for (int j = 0; j < 16; j++) {
        f2 qj = ((const f2*)qs)[j];
        q2 += qj * qj;
    }
    float q_t = sqrtf(q2.x + q2.y + 1.0f);

    int r0 = offsets[n], r1 = offsets[n + 1];
    float acc[34] __attribute__((aligned(16)));   // space[0..31], time[32], pad[33]
#pragma unroll
    for (int i = 0; i < 34; i++) acc[i] = 0.f;

    int e = r0 + t;
    int off = (e < r1) ? soff[e] : 0;
    for (; e < r1; e += 4) {
        int offn = (e + 4 < r1) ? soff[e + 4] : 0;   // prefetch next row offset
        const float* kr = kh + off + h * 32;
        const float* vr = vh + off + h * 32;
        float ks[32] __attribute__((aligned(16)));
        float vs[32] __attribute__((aligned(16)));
#pragma unroll
        for (int i = 0; i < 8; i++) *(float4*)&ks[i * 4] = *(const float4*)&kr[i * 4];
#pragma unroll
        for (int i = 0; i < 8; i++) *(float4*)&vs[i * 4] = *(const float4*)&vr[i * 4];

        f2 d2 = {0.f, 0.f}, k2 = {0.f, 0.f};
#pragma unroll
        for (int j = 0; j < 16; j++) {
            f2 kj = ((const f2*)ks)[j];
            d2 += ((const f2*)qs)[j] * kj;
            k2 += kj * kj;
        }
        float k_t = sqrtf(k2.x + k2.y + 1.0f);
        // score = (2 + 2*cinner)/sqrt(32); cinner = <q_s,k_s> - q_t*k_t <= -1 => score <= 0
        float s = (1.0f + d2.x + d2.y - q_t * k_t) * 0.35355339059327373f;
        float p = __expf(s);   // in (0,1], no max subtraction needed

        f2 v2 = {0.f, 0.f};
#pragma unroll
        for (int j = 0; j < 16; j++) {
            f2 vj = ((const f2*)vs)[j];
            v2 += vj * vj;
            ((f2*)acc)[j] += vj * p;
        }
        acc[32] = fmaf(p, sqrtf(v2.x + v2.y + 1.0f), acc[32]);
        off = offn;
    }

    // merge the 4 edge-quarters (lane bits 2,3)
#pragma unroll
    for (int i = 0; i < 33; i++) {
        float a = acc[i];
        a += __shfl_xor(a, 4);
        a += __shfl_xor(a, 8);
        acc[i] = a;
    }

    // out = acc / sqrt(clip(|<acc,acc>_L|, 1e-8))  (softmax denom cancels)
    float ss = 0.f;
#pragma unroll
    for (int j = 0; j < 32; j++) ss += acc[j] * acc[j];
    float c = ss - acc[32] * acc[32];
    float d = sqrtf(fmaxf(fabsf(c), 1e-8f));
    float inv = 1.0f / d;

    // each t stores its 8-float slice of the space part (static indices only)
    float* orow = mid + (size_t)n * 128 + h * 32;
    if (t == 0) {
        float4 o0 = {acc[0] * inv, acc[1] * inv, acc[2] * inv, acc[3] * inv};
        float4 o1 = {acc[4] * inv, acc[5] * inv, acc[6] * inv, acc[7] * inv};
        *(float4*)&orow[0] = o0;
        *(float4*)&orow[4] = o1;
    } else if (t == 1) {
        float4 o0 = {acc[8] * inv, acc[9] * inv, acc[10] * inv, acc[11] * inv};
        float4 o1 = {acc[12] * inv, acc[13] * inv, acc[14] * inv, acc[15] * inv};
        *(float4*)&orow[8] = o0;
        *(float4*)&orow[12] = o1;
    } else if (t == 2) {
        float4 o0 = {acc[16] * inv, acc[17] * inv, acc[18] * inv, acc[19] * inv};
        float4 o1 = {acc[20] * inv, acc[21] * inv, acc[22] * inv, acc[23] * inv};
        *(float4*)&orow[16] = o0;
        *(float4*)&orow[20] = o1;
    } else {
        float4 o0 = {acc[24] * inv, acc[25] * inv, acc[26] * inv, acc[27] * inv};
        float4 o1 = {acc[28] * inv, acc[29] * inv, acc[30] * inv, acc[31] * inv};
        *(float4*)&orow[24] = o0;
        *(float4*)&orow[28] = o1;
    }
}

// ---- K4: final hyperbolic linear: 32 nodes/block, 128 threads (one per out-dim) ----
__global__ __launch_bounds__(128) void final_linear(const float* __restrict__ mid,
                                                    const float* __restrict__ WoT,
                                                    const float* __restrict__ bo,
                                                    float* __restrict__ out, int Nn) {
    __shared__ __align__(16) float xl[32][132];
    int tid = threadIdx.x;
    int nb = blockIdx.x * 32;
#pragma unroll
    for (int i = 0; i < 32; i++) {
        int n = nb + i;
        xl[i][1 + tid] = (n < Nn) ? mid[(size_t)n * 128 + tid] : 0.f;
    }
    __syncthreads();
    int nl = tid >> 2, sub = tid & 3;
    {
        float s = 0.f;
#pragma unroll
        for (int j = 0; j < 32; j++) {
            float v = xl[nl][1 + sub * 32 + j];
            s += v * v;
        }
        s += __shfl_xor(s, 1);
        s += __shfl_xor(s, 2);
        if (sub == 0) xl[nl][0] = sqrtf(s + 1.0f);
    }
    __syncthreads();

    float bv = bo[tid];
    float acc[32];
#pragma unroll
    for (int i = 0; i < 32; i++) acc[i] = bv;

    for (int k = 0; k < 128; k += 4) {
        float w0 = WoT[(size_t)(k + 0) * 128 + tid];
        float w1 = WoT[(size_t)(k + 1) * 128 + tid];
        float w2 = WoT[(size_t)(k + 2) * 128 + tid];
        float w3 = WoT[(size_t)(k + 3) * 128 + tid];
#pragma unroll
        for (int i = 0; i < 32; i++) {
            float4 xv = *(const float4*)&xl[i][k];   // broadcast reads
            acc[i] += w0 * xv.x + w1 * xv.y + w2 * xv.z + w3 * xv.w;
        }
    }
    {
        float w = WoT[(size_t)128 * 128 + tid];
#pragma unroll
        for (int i = 0; i < 32; i++) acc[i] += w * xl[i][128];
    }
    __syncthreads();
#pragma unroll
    for (int i = 0; i < 32; i++) {
        int n = nb + i;
        if (n < Nn) out[(size_t)n * 129 + 1 + tid] = acc[i];
        xl[i][tid] = acc[i] * acc[i];
    }
    __syncthreads();
    {
        float s = 0.f;
#pragma unroll
        for (int j = 0; j < 32; j++) s += xl[nl][sub * 32 + j];
        s += __shfl_xor(s, 1);
        s += __shfl_xor(s, 2);
        if (sub == 0 && (nb + nl) < Nn) out[(size_t)(nb + nl) * 129] = sqrtf(s + 1.0f);
    }
}

// legacy single-block scan fallback (only used if N > 65536)
__global__ __launch_bounds__(1024) void scan_kernel(const int* __restrict__ deg,
                                                    int* __restrict__ offsets, int n) {
    __shared__ int wsum[16];
    __shared__ int carry_s;
    int tid = threadIdx.x;
    int lane = tid & 63, wid = tid >> 6;
    if (tid == 0) carry_s = 0;
    __syncthreads();
    for (int base = 0; base < n; base += 1024) {
        int idx = base + tid;
        int v = (idx < n) ? deg[idx] : 0;
        int x = v;
#pragma unroll
        for (int d = 1; d < 64; d <<= 1) {
            int y = __shfl_up(x, d, 64);
            if (lane >= d) x += y;
        }
        if (lane == 63) wsum[wid] = x;
        __syncthreads();
        if (wid == 0) {
            int s = (lane < 16) ? wsum[lane] : 0;
#pragma unroll
            for (int d = 1; d < 16; d <<= 1) {
                int y = __shfl_up(s, d, 64);
                if (lane >= d) s += y;
            }
            if (lane < 16) wsum[lane] = s;
        }
        __syncthreads();
        int waveoff = (wid > 0) ? wsum[wid - 1] : 0;
        int excl = carry_s + waveoff + x - v;
        if (idx < n) offsets[idx] = excl;
        __syncthreads();
        if (tid == 0) carry_s += wsum[15];
        __syncthreads();
    }
    if (tid == 0) offsets[n] = carry_s;
}

extern "C" void kernel_launch(void* const* d_in, const int* in_sizes, int n_in,
                              void* d_out, int out_size, void* d_ws, size_t ws_size,
                              hipStream_t stream) {
    const float* x  = (const float*)d_in[0];
    const int*   ei = (const int*)d_in[1];
    const float* Wq = (const float*)d_in[2];
    const float* bq = (const float*)d_in[3];
    const float* Wk = (const float*)d_in[4];
    const float* bk = (const float*)d_in[5];
    const float* Wv = (const float*)d_in[6];
    const float* bv = (const float*)d_in[7];
    const float* Wo = (const float*)d_in[8];
    const float* bo = (const float*)d_in[9];
    float* out = (float*)d_out;

    const int N = in_sizes[0] / 129;
    const int E = in_sizes[1] / 2;

    // workspace layout (256B-aligned bump allocator)
    char* w = (char*)d_ws;
    size_t off = 0;
    auto alloc = [&](size_t bytes) {
        void* p = w + off;
        off += (bytes + 255) & ~(size_t)255;
        return p;
    };
    float* qh       = (float*)alloc((size_t)N * 128 * 4);
    float* kh       = (float*)alloc((size_t)N * 128 * 4);
    float* vh       = (float*)alloc((size_t)N * 128 * 4);
    float* mid      = (float*)alloc((size_t)N * 128 * 4);
    float* WT       = (float*)alloc(129 * 384 * 4);
    float* bias     = (float*)alloc(384 * 4);
    float* WoT      = (float*)alloc(129 * 128 * 4);
    int*   offsets  = (int*)alloc((size_t)(N + 1) * 4);
    int*   degcur   = (int*)alloc((size_t)2 * N * 4);  // deg[N] + cursor[N]
    int*   deg      = degcur;
    int*   cursor   = degcur + N;
    int*   partials = (int*)alloc(256 * 4);
    int*   srcs     = (int*)alloc((size_t)E * 4);

    hipMemsetAsync(degcur, 0, (size_t)2 * N * 4, stream);

    prep_kernel<<<260, 256, 0, stream>>>(Wq, bq, Wk, bk, Wv, bv, Wo, WT, bias, WoT);

    dim3 g1((N + 63) / 64, 6);
    qkv_gemm<<<g1, 256, 0, stream>>>(x, WT, bias, qh, kh, vh, N);

    count_kernel<<<(E + 255) / 256, 256, 0, stream>>>(ei, deg, E);

    int nb = (N + 255) / 256;
    if (nb <= 256) {
        scan_blocks<<<nb, 256, 0, stream>>>(deg, offsets, partials, N);
        scan_partials<<<1, 256, 0, stream>>>(partials, offsets + N, nb);
        scan_add<<<nb, 256, 0, stream>>>(offsets, partials, N);
    } else {
        scan_kernel<<<1, 1024, 0, stream>>>(deg, offsets, N);
    }

    fill_kernel<<<(E + 255) / 256, 256, 0, stream>>>(ei, offsets, cursor, srcs, E);

    attn_kernel<<<(N * 16 + 255) / 256, 256, 0, stream>>>(qh, kh, vh, offsets, srcs, mid, N);

    final_linear<<<(N + 31) / 32, 128, 0, stream>>>(mid, WoT, bo, out, N);
}

// Round 6
// 475.128 us; speedup vs baseline: 1.6572x; 1.1529x over previous
//
#include <hip/hip_runtime.h>
#include <hip/hip_bf16.h>
#include <math.h>

// Problem constants (from reference): D=128, H=4, HD=32, K=1.0
// Derived at runtime: N = in_sizes[0]/129, E = in_sizes[1]/2.
//
// Pipeline:
//  P0  prep:      build WT[129][384] (qkv weights transposed, channel-major),
//                 bias[384], WoT[129][128]
//  K1  qkv_gemm:  q -> qh[N][128]; k,v interleaved -> kv[N][256] (k: 0..127, v: 128..255);
//                 per-head time coords fused in epilogue -> tvec[N][16] = {kt[4],vt[4],qt[4],pad}
//  K2a count:     deg[dst]++
//  K2b-d scan:    hierarchical exclusive scan -> offsets (CSR)
//  K2e fill:      srcs grouped by dst, pre-scaled by 256 (kv row stride)
//  K3  attn:      16 lanes cooperatively process one edge (all 4 heads): lane-consecutive
//                 1KB kv row loads (8 cache-line transactions/edge vs ~68 before);
//                 head dots via 8-lane shfl_xor tree. Wave = 1 node x 4 edge-quarters.
//                 No max subtraction needed (<q,k>_L <= -1 => score <= 0 => exp in (0,1]);
//                 softmax denominator cancels in Lorentz normalization.
//  K4  final:     out = hyp_linear(concat(time,space), Wo, bo)

__global__ void prep_kernel(const float* __restrict__ Wq, const float* __restrict__ bq,
                            const float* __restrict__ Wk, const float* __restrict__ bk,
                            const float* __restrict__ Wv, const float* __restrict__ bv,
                            const float* __restrict__ Wo,
                            float* __restrict__ WT, float* __restrict__ bias,
                            float* __restrict__ WoT) {
    const int T1 = 129 * 384;
    const int T2 = T1 + 384;
    const int T3 = T2 + 129 * 128;
    for (int i = blockIdx.x * blockDim.x + threadIdx.x; i < T3; i += gridDim.x * blockDim.x) {
        if (i < T1) {
            int k = i / 384, o = i % 384;
            const float* W = (o < 128) ? Wq : (o < 256 ? Wk : Wv);
            int r = o & 127;
            WT[i] = W[(size_t)r * 129 + k];
        } else if (i < T2) {
            int o = i - T1;
            const float* b = (o < 128) ? bq : (o < 256 ? bk : bv);
            bias[o] = b[o & 127];
        } else {
            int j = i - T2;
            int k = j >> 7, o = j & 127;
            WoT[j] = Wo[(size_t)o * 129 + k];
        }
    }
}

// ---- K1: C[n][ch] = sum_k x[n][k] * WT[k][ch], ch in [0,384) ----
// 64-node x 64-channel tile; 64 channels = 2 complete heads of one tensor (q, k, or v).
// Epilogue computes per-head time = sqrt(|space|^2+1) via 8-lane shfl reduction.
__global__ __launch_bounds__(256) void qkv_gemm(const float* __restrict__ x,
                                                const float* __restrict__ WT,
                                                const float* __restrict__ bias,
                                                float* __restrict__ qh, float* __restrict__ kv,
                                                float* __restrict__ tvec, int Nn) {
    __shared__ __align__(16) float xs[16][68];
    __shared__ __align__(16) float ws[16][64];
    int tid = threadIdx.x;
    int tx = tid & 15, ty = tid >> 4;
    int nbase = blockIdx.x * 64;
    int cbase = blockIdx.y * 64;
    float acc[4][4];
#pragma unroll
    for (int i = 0; i < 4; i++)
#pragma unroll
        for (int j = 0; j < 4; j++) acc[i][j] = 0.f;

    for (int k0 = 0; k0 < 129; k0 += 16) {
#pragma unroll
        for (int i = tid; i < 64 * 16; i += 256) {
            int nl = i >> 4, kk = i & 15;
            int n = nbase + nl, k = k0 + kk;
            xs[kk][nl] = (n < Nn && k < 129) ? x[(size_t)n * 129 + k] : 0.f;
        }
#pragma unroll
        for (int i = tid; i < 16 * 64; i += 256) {
            int kk = i >> 6, c = i & 63;
            int k = k0 + kk;
            ws[kk][c] = (k < 129) ? WT[(size_t)k * 384 + cbase + c] : 0.f;
        }
        __syncthreads();
#pragma unroll
        for (int kk = 0; kk < 16; kk++) {
            float4 a = *(const float4*)&xs[kk][ty * 4];
            float4 b = *(const float4*)&ws[kk][tx * 4];
            float av[4] = {a.x, a.y, a.z, a.w};
            float bw[4] = {b.x, b.y, b.z, b.w};
#pragma unroll
            for (int i = 0; i < 4; i++)
#pragma unroll
                for (int j = 0; j < 4; j++) acc[i][j] += av[i] * bw[j];
        }
        __syncthreads();
    }
    // epilogue: float4 store + fused per-head time coordinate
    int ch0 = cbase + tx * 4;
    float4 bb = *(const float4*)&bias[ch0];
    int t = cbase >> 7;                     // 0=q, 1=k, 2=v (uniform per block)
    int r = ch0 & 127;
    int hh = r >> 5;                        // head index 0..3
#pragma unroll
    for (int i = 0; i < 4; i++) {
        int n = nbase + ty * 4 + i;
        float4 o;
        o.x = acc[i][0] + bb.x;
        o.y = acc[i][1] + bb.y;
        o.z = acc[i][2] + bb.z;
        o.w = acc[i][3] + bb.w;
        // head sum-of-squares over 8 tx-lanes (32 channels)
        float s = o.x * o.x + o.y * o.y + o.z * o.z + o.w * o.w;
        s += __shfl_xor(s, 1);
        s += __shfl_xor(s, 2);
        s += __shfl_xor(s, 4);
        if (n < Nn) {
            if (t == 0) {
                *(float4*)&qh[(size_t)n * 128 + r] = o;
                if ((tx & 7) == 0) tvec[n * 16 + 8 + hh] = sqrtf(s + 1.0f);
            } else if (t == 1) {
                *(float4*)&kv[(size_t)n * 256 + r] = o;
                if ((tx & 7) == 0) tvec[n * 16 + hh] = sqrtf(s + 1.0f);
            } else {
                *(float4*)&kv[(size_t)n * 256 + 128 + r] = o;
                if ((tx & 7) == 0) tvec[n * 16 + 4 + hh] = sqrtf(s + 1.0f);
            }
        }
    }
}

__global__ void count_kernel(const int* __restrict__ ei, int* __restrict__ deg, int E) {
    int e = blockIdx.x * blockDim.x + threadIdx.x;
    if (e < E) atomicAdd(&deg[ei[E + e]], 1);
}

// ---- hierarchical exclusive scan (N <= 256*256) ----
__global__ __launch_bounds__(256) void scan_blocks(const int* __restrict__ deg,
                                                   int* __restrict__ offsets,
                                                   int* __restrict__ partials, int n) {
    __shared__ int wsum[4];
    int tid = threadIdx.x;
    int idx = blockIdx.x * 256 + tid;
    int lane = tid & 63, wid = tid >> 6;
    int v = (idx < n) ? deg[idx] : 0;
    int x = v;
#pragma unroll
    for (int d = 1; d < 64; d <<= 1) {
        int y = __shfl_up(x, d, 64);
        if (lane >= d) x += y;
    }
    if (lane == 63) wsum[wid] = x;
    __syncthreads();
    if (tid == 0) {
        int s = 0;
#pragma unroll
        for (int i = 0; i < 4; i++) { int tv = wsum[i]; wsum[i] = s; s += tv; }
    }
    __syncthreads();
    int excl = wsum[wid] + x - v;
    if (idx < n) offsets[idx] = excl;
    if (tid == 255) partials[blockIdx.x] = excl + v;
}

__global__ __launch_bounds__(256) void scan_partials(int* __restrict__ partials,
                                                     int* __restrict__ total_out, int nb) {
    __shared__ int wsum[4];
    int tid = threadIdx.x;
    int lane = tid & 63, wid = tid >> 6;
    int v = (tid < nb) ? partials[tid] : 0;
    int x = v;
#pragma unroll
    for (int d = 1; d < 64; d <<= 1) {
        int y = __shfl_up(x, d, 64);
        if (lane >= d) x += y;
    }
    if (lane == 63) wsum[wid] = x;
    __syncthreads();
    if (tid == 0) {
        int s = 0;
#pragma unroll
        for (int i = 0; i < 4; i++) { int tv = wsum[i]; wsum[i] = s; s += tv; }
    }
    __syncthreads();
    int excl = wsum[wid] + x - v;
    if (tid < nb) partials[tid] = excl;
    if (tid == 255) *total_out = excl + v;
}

__global__ void scan_add(int* __restrict__ offsets, const int* __restrict__ partials, int n) {
    int idx = blockIdx.x * blockDim.x + threadIdx.x;
    if (idx < n) offsets[idx] += partials[blockIdx.x];
}

__global__ void fill_kernel(const int* __restrict__ ei, const int* __restrict__ offsets,
                            int* __restrict__ cursor, int* __restrict__ srcs, int E) {
    int e = blockIdx.x * blockDim.x + threadIdx.x;
    if (e < E) {
        int src = ei[e];
        int dst = ei[E + e];
        int pos = atomicAdd(&cursor[dst], 1);
        srcs[offsets[dst] + pos] = src * 256;   // pre-scaled kv row offset
    }
}

// ---- K3: cooperative-gather attention ----
// Wave = 1 dst node. 4 groups of 16 consecutive lanes, group t handles edges r0+t, r0+t+4, ...
// Per edge: 4 lane-consecutive float4 loads fetch the whole 1KB kv row (8 line transactions).
// Lane l holds k floats {l*4..l*4+3} (head l>>3) and {64+l*4..} (head 2+(l>>3)); dots are
// reduced over 8-lane shfl_xor trees; per-head kt/vt broadcast from the tvec row.
__global__ __launch_bounds__(256) void attn_kernel(const float* __restrict__ qh,
                                                   const float* __restrict__ kv,
                                                   const float* __restrict__ tvec,
                                                   const int* __restrict__ offsets,
                                                   const int* __restrict__ soff,
                                                   float* __restrict__ mid, int Nn) {
    int tid = threadIdx.x;
    int n = (blockIdx.x * blockDim.x + tid) >> 6;   // one node per wave
    if (n >= Nn) return;
    int lw = tid & 63;
    int t = lw >> 4;            // edge-quarter 0..3
    int l = lw & 15;            // lane within group
    int base = lw & 48;         // group's first lane (absolute)
    int ha = l >> 3;            // slot-A head (0/1); slot-B head = 2+ha

    float4 qa = *(const float4*)&qh[(size_t)n * 128 + l * 4];
    float4 qb = *(const float4*)&qh[(size_t)n * 128 + 64 + l * 4];
    float qta = tvec[n * 16 + 8 + ha];
    float qtb = tvec[n * 16 + 10 + ha];

    float4 acc_a = {0.f, 0.f, 0.f, 0.f}, acc_b = {0.f, 0.f, 0.f, 0.f};
    float acc_ta = 0.f, acc_tb = 0.f;

    int r0 = offsets[n], r1 = offsets[n + 1];
    int e = r0 + t;
    int off = (e < r1) ? soff[e] : 0;
    for (; e < r1; e += 4) {
        int offn = (e + 4 < r1) ? soff[e + 4] : 0;   // prefetch next row offset
        const float* row = kv + off;
        float4 k0 = *(const float4*)&row[l * 4];
        float4 k1 = *(const float4*)&row[64 + l * 4];
        float4 v0 = *(const float4*)&row[128 + l * 4];
        float4 v1 = *(const float4*)&row[192 + l * 4];
        float tv = tvec[(off >> 4) + (l & 7)];       // kt[0..3], vt[0..3]

        float pa = qa.x * k0.x + qa.y * k0.y + qa.z * k0.z + qa.w * k0.w;
        float pb = qb.x * k1.x + qb.y * k1.y + qb.z * k1.z + qb.w * k1.w;
        pa += __shfl_xor(pa, 1);
        pb += __shfl_xor(pb, 1);
        pa += __shfl_xor(pa, 2);
        pb += __shfl_xor(pb, 2);
        pa += __shfl_xor(pa, 4);
        pb += __shfl_xor(pb, 4);
        float kta = __shfl(tv, base + ha);
        float ktb = __shfl(tv, base + 2 + ha);
        float vta = __shfl(tv, base + 4 + ha);
        float vtb = __shfl(tv, base + 6 + ha);
        // score = (2 + 2*cinner)/sqrt(32), cinner = <q_s,k_s> - q_t*k_t <= -1 => score <= 0
        float sa = (1.0f + pa - qta * kta) * 0.35355339059327373f;
        float sb = (1.0f + pb - qtb * ktb) * 0.35355339059327373f;
        float wa = __expf(sa), wb = __expf(sb);
        acc_a.x += wa * v0.x; acc_a.y += wa * v0.y; acc_a.z += wa * v0.z; acc_a.w += wa * v0.w;
        acc_b.x += wb * v1.x; acc_b.y += wb * v1.y; acc_b.z += wb * v1.z; acc_b.w += wb * v1.w;
        acc_ta = fmaf(wa, vta, acc_ta);
        acc_tb = fmaf(wb, vtb, acc_tb);
        off = offn;
    }

    // merge the 4 edge-quarters
#define MRG(x) x += __shfl_xor(x, 16); x += __shfl_xor(x, 32);
    MRG(acc_a.x) MRG(acc_a.y) MRG(acc_a.z) MRG(acc_a.w)
    MRG(acc_b.x) MRG(acc_b.y) MRG(acc_b.z) MRG(acc_b.w)
    MRG(acc_ta) MRG(acc_tb)
#undef MRG

    // per-head Lorentz normalization: out = acc / sqrt(clip(|<acc,acc>_L|, 1e-8))
    float ssa = acc_a.x * acc_a.x + acc_a.y * acc_a.y + acc_a.z * acc_a.z + acc_a.w * acc_a.w;
    float ssb = acc_b.x * acc_b.x + acc_b.y * acc_b.y + acc_b.z * acc_b.z + acc_b.w * acc_b.w;
    ssa += __shfl_xor(ssa, 1);
    ssb += __shfl_xor(ssb, 1);
    ssa += __shfl_xor(ssa, 2);
    ssb += __shfl_xor(ssb, 2);
    ssa += __shfl_xor(ssa, 4);
    ssb += __shfl_xor(ssb, 4);
    float ca = ssa - acc_ta * acc_ta;
    float cb = ssb - acc_tb * acc_tb;
    float inva = 1.0f / sqrtf(fmaxf(fabsf(ca), 1e-8f));
    float invb = 1.0f / sqrtf(fmaxf(fabsf(cb), 1e-8f));

    if (t == 0) {
        float4 oa = {acc_a.x * inva, acc_a.y * inva, acc_a.z * inva, acc_a.w * inva};
        float4 ob = {acc_b.x * invb, acc_b.y * invb, acc_b.z * invb, acc_b.w * invb};
        *(float4*)&mid[(size_t)n * 128 + l * 4] = oa;
        *(float4*)&mid[(size_t)n * 128 + 64 + l * 4] = ob;
    }
}

// ---- K4: final hyperbolic linear: 32 nodes/block, 128 threads (one per out-dim) ----
__global__ __launch_bounds__(128) void final_linear(const float* __restrict__ mid,
                                                    const float* __restrict__ WoT,
                                                    const float* __restrict__ bo,
                                                    float* __restrict__ out, int Nn) {
    __shared__ __align__(16) float xl[32][132];
    int tid = threadIdx.x;
    int nb = blockIdx.x * 32;
#pragma unroll
    for (int i = 0; i < 32; i++) {
        int n = nb + i;
        xl[i][1 + tid] = (n < Nn) ? mid[(size_t)n * 128 + tid] : 0.f;
    }
    __syncthreads();
    int nl = tid >> 2, sub = tid & 3;
    {
        float s = 0.f;
#pragma unroll
        for (int j = 0; j < 32; j++) {
            float v = xl[nl][1 + sub * 32 + j];
            s += v * v;
        }
        s += __shfl_xor(s, 1);
        s += __shfl_xor(s, 2);
        if (sub == 0) xl[nl][0] = sqrtf(s + 1.0f);
    }
    __syncthreads();

    float bv = bo[tid];
    float acc[32];
#pragma unroll
    for (int i = 0; i < 32; i++) acc[i] = bv;

    for (int k = 0; k < 128; k += 4) {
        float w0 = WoT[(size_t)(k + 0) * 128 + tid];
        float w1 = WoT[(size_t)(k + 1) * 128 + tid];
        float w2 = WoT[(size_t)(k + 2) * 128 + tid];
        float w3 = WoT[(size_t)(k + 3) * 128 + tid];
#pragma unroll
        for (int i = 0; i < 32; i++) {
            float4 xv = *(const float4*)&xl[i][k];   // broadcast reads
            acc[i] += w0 * xv.x + w1 * xv.y + w2 * xv.z + w3 * xv.w;
        }
    }
    {
        float w = WoT[(size_t)128 * 128 + tid];
#pragma unroll
        for (int i = 0; i < 32; i++) acc[i] += w * xl[i][128];
    }
    __syncthreads();
#pragma unroll
    for (int i = 0; i < 32; i++) {
        int n = nb + i;
        if (n < Nn) out[(size_t)n * 129 + 1 + tid] = acc[i];
        xl[i][tid] = acc[i] * acc[i];
    }
    __syncthreads();
    {
        float s = 0.f;
#pragma unroll
        for (int j = 0; j < 32; j++) s += xl[nl][sub * 32 + j];
        s += __shfl_xor(s, 1);
        s += __shfl_xor(s, 2);
        if (sub == 0 && (nb + nl) < Nn) out[(size_t)(nb + nl) * 129] = sqrtf(s + 1.0f);
    }
}

// legacy single-block scan fallback (only used if N > 65536)
__global__ __launch_bounds__(1024) void scan_kernel(const int* __restrict__ deg,
                                                    int* __restrict__ offsets, int n) {
    __shared__ int wsum[16];
    __shared__ int carry_s;
    int tid = threadIdx.x;
    int lane = tid & 63, wid = tid >> 6;
    if (tid == 0) carry_s = 0;
    __syncthreads();
    for (int base = 0; base < n; base += 1024) {
        int idx = base + tid;
        int v = (idx < n) ? deg[idx] : 0;
        int x = v;
#pragma unroll
        for (int d = 1; d < 64; d <<= 1) {
            int y = __shfl_up(x, d, 64);
            if (lane >= d) x += y;
        }
        if (lane == 63) wsum[wid] = x;
        __syncthreads();
        if (wid == 0) {
            int s = (lane < 16) ? wsum[lane] : 0;
#pragma unroll
            for (int d = 1; d < 16; d <<= 1) {
                int y = __shfl_up(s, d, 64);
                if (lane >= d) s += y;
            }
            if (lane < 16) wsum[lane] = s;
        }
        __syncthreads();
        int waveoff = (wid > 0) ? wsum[wid - 1] : 0;
        int excl = carry_s + waveoff + x - v;
        if (idx < n) offsets[idx] = excl;
        __syncthreads();
        if (tid == 0) carry_s += wsum[15];
        __syncthreads();
    }
    if (tid == 0) offsets[n] = carry_s;
}

extern "C" void kernel_launch(void* const* d_in, const int* in_sizes, int n_in,
                              void* d_out, int out_size, void* d_ws, size_t ws_size,
                              hipStream_t stream) {
    const float* x  = (const float*)d_in[0];
    const int*   ei = (const int*)d_in[1];
    const float* Wq = (const float*)d_in[2];
    const float* bq = (const float*)d_in[3];
    const float* Wk = (const float*)d_in[4];
    const float* bk = (const float*)d_in[5];
    const float* Wv = (const float*)d_in[6];
    const float* bv = (const float*)d_in[7];
    const float* Wo = (const float*)d_in[8];
    const float* bo = (const float*)d_in[9];
    float* out = (float*)d_out;

    const int N = in_sizes[0] / 129;
    const int E = in_sizes[1] / 2;

    // workspace layout (256B-aligned bump allocator)
    char* w = (char*)d_ws;
    size_t off = 0;
    auto alloc = [&](size_t bytes) {
        void* p = w + off;
        off += (bytes + 255) & ~(size_t)255;
        return p;
    };
    float* qh       = (float*)alloc((size_t)N * 128 * 4);
    float* kv       = (float*)alloc((size_t)N * 256 * 4);
    float* tvec     = (float*)alloc((size_t)N * 16 * 4);
    float* mid      = (float*)alloc((size_t)N * 128 * 4);
    float* WT       = (float*)alloc(129 * 384 * 4);
    float* bias     = (float*)alloc(384 * 4);
    float* WoT      = (float*)alloc(129 * 128 * 4);
    int*   offsets  = (int*)alloc((size_t)(N + 1) * 4);
    int*   degcur   = (int*)alloc((size_t)2 * N * 4);  // deg[N] + cursor[N]
    int*   deg      = degcur;
    int*   cursor   = degcur + N;
    int*   partials = (int*)alloc(256 * 4);
    int*   srcs     = (int*)alloc((size_t)E * 4);

    hipMemsetAsync(degcur, 0, (size_t)2 * N * 4, stream);

    prep_kernel<<<260, 256, 0, stream>>>(Wq, bq, Wk, bk, Wv, bv, Wo, WT, bias, WoT);

    dim3 g1((N + 63) / 64, 6);
    qkv_gemm<<<g1, 256, 0, stream>>>(x, WT, bias, qh, kv, tvec, N);

    count_kernel<<<(E + 255) / 256, 256, 0, stream>>>(ei, deg, E);

    int nb = (N + 255) / 256;
    if (nb <= 256) {
        scan_blocks<<<nb, 256, 0, stream>>>(deg, offsets, partials, N);
        scan_partials<<<1, 256, 0, stream>>>(partials, offsets + N, nb);
        scan_add<<<nb, 256, 0, stream>>>(offsets, partials, N);
    } else {
        scan_kernel<<<1, 1024, 0, stream>>>(deg, offsets, N);
    }

    fill_kernel<<<(E + 255) / 256, 256, 0, stream>>>(ei, offsets, cursor, srcs, E);

    attn_kernel<<<(N + 3) / 4, 256, 0, stream>>>(qh, kv, tvec, offsets, srcs, mid, N);

    final_linear<<<(N + 31) / 32, 128, 0, stream>>>(mid, WoT, bo, out, N);
}

// Round 7
// 459.362 us; speedup vs baseline: 1.7141x; 1.0343x over previous
//
#include <hip/hip_runtime.h>
#include <hip/hip_bf16.h>
#include <math.h>

// Problem constants (from reference): D=128, H=4, HD=32, K=1.0
// Derived at runtime: N = in_sizes[0]/129, E = in_sizes[1]/2.
//
// Pipeline:
//  P0  prep:      build WT[129][384] (qkv weights transposed, channel-major),
//                 bias[384], WoT[129][128]
//  K1  qkv_gemm:  128x128 block tile, 8x8/thread fp32 GEMM. q -> qh[N][128];
//                 k,v interleaved -> kv[N][256]; per-head time coords -> tvec[N][16]
//  K2a count:     deg[dst]++
//  K2b-d scan:    hierarchical exclusive scan -> offsets (CSR)
//  K2e fill:      srcs grouped by dst, pre-scaled by 256 (kv row stride)
//  K3  attn:      16 lanes cooperatively process one edge (all 4 heads): lane-consecutive
//                 1KB kv row loads; head dots via 8-lane shfl_xor tree.
//                 Wave = 1 node x 4 edge-quarters. No max subtraction needed
//                 (<q,k>_L <= -1 => score <= 0 => exp in (0,1]); softmax denominator
//                 cancels in the Lorentz normalization.
//  K4  final:     out = hyp_linear(concat(time,space), Wo, bo)

__global__ void prep_kernel(const float* __restrict__ Wq, const float* __restrict__ bq,
                            const float* __restrict__ Wk, const float* __restrict__ bk,
                            const float* __restrict__ Wv, const float* __restrict__ bv,
                            const float* __restrict__ Wo,
                            float* __restrict__ WT, float* __restrict__ bias,
                            float* __restrict__ WoT) {
    const int T1 = 129 * 384;
    const int T2 = T1 + 384;
    const int T3 = T2 + 129 * 128;
    for (int i = blockIdx.x * blockDim.x + threadIdx.x; i < T3; i += gridDim.x * blockDim.x) {
        if (i < T1) {
            int k = i / 384, o = i % 384;
            const float* W = (o < 128) ? Wq : (o < 256 ? Wk : Wv);
            int r = o & 127;
            WT[i] = W[(size_t)r * 129 + k];
        } else if (i < T2) {
            int o = i - T1;
            const float* b = (o < 128) ? bq : (o < 256 ? bk : bv);
            bias[o] = b[o & 127];
        } else {
            int j = i - T2;
            int k = j >> 7, o = j & 127;
            WoT[j] = Wo[(size_t)o * 129 + k];
        }
    }
}

// ---- K1: 128-node x 128-channel tile per block, 8x8 per thread ----
// blockIdx.y = tensor t (0=q,1=k,2=v); thread (tx,ty) owns rows ty*8..+7, cols tx*8..+7.
// LDS layouts are 2-way-conflict-max (free on CDNA4):
//   xs[16][132] scalar-staged (banks (4*kk+r)&31), ws[16][132] float4-staged contiguous.
// Epilogue: bias add, per-head time=sqrt(|space|^2+1) via 4-lane shfl (8 cols/thread all in
// head tx>>2), float4 stores.
__global__ __launch_bounds__(256) void qkv_gemm(const float* __restrict__ x,
                                                const float* __restrict__ WT,
                                                const float* __restrict__ bias,
                                                float* __restrict__ qh, float* __restrict__ kv,
                                                float* __restrict__ tvec, int Nn) {
    __shared__ __align__(16) float xs[16][132];
    __shared__ __align__(16) float ws[16][132];
    int tid = threadIdx.x;
    int tx = tid & 15, ty = tid >> 4;
    int nbase = blockIdx.x * 128;
    int cbase = blockIdx.y * 128;

    float acc[8][8];
#pragma unroll
    for (int i = 0; i < 8; i++)
#pragma unroll
        for (int j = 0; j < 8; j++) acc[i][j] = 0.f;

    for (int k0 = 0; k0 < 129; k0 += 16) {
        // stage x tile: 128 rows x 16 k, scalar coalesced-by-k (129 stride is odd -> no float4)
#pragma unroll
        for (int it = 0; it < 8; it++) {
            int i = tid + it * 256;          // 0..2047
            int kk = i & 15, r = i >> 4;
            int n = nbase + r, k = k0 + kk;
            xs[kk][r] = (n < Nn && k < 129) ? x[(size_t)n * 129 + k] : 0.f;
        }
        // stage w tile: 16 k x 128 c, float4
#pragma unroll
        for (int it = 0; it < 2; it++) {
            int i = tid + it * 256;          // 0..511
            int c4 = i & 31, kk = i >> 5;
            int k = k0 + kk;
            float4 wv = {0.f, 0.f, 0.f, 0.f};
            if (k < 129) wv = *(const float4*)&WT[(size_t)k * 384 + cbase + c4 * 4];
            *(float4*)&ws[kk][c4 * 4] = wv;
        }
        __syncthreads();
#pragma unroll
        for (int kk = 0; kk < 16; kk++) {
            float4 a0 = *(const float4*)&xs[kk][ty * 8];
            float4 a1 = *(const float4*)&xs[kk][ty * 8 + 4];
            float4 b0 = *(const float4*)&ws[kk][tx * 8];
            float4 b1 = *(const float4*)&ws[kk][tx * 8 + 4];
            float av[8] = {a0.x, a0.y, a0.z, a0.w, a1.x, a1.y, a1.z, a1.w};
            float bw[8] = {b0.x, b0.y, b0.z, b0.w, b1.x, b1.y, b1.z, b1.w};
#pragma unroll
            for (int i = 0; i < 8; i++)
#pragma unroll
                for (int j = 0; j < 8; j++) acc[i][j] = fmaf(av[i], bw[j], acc[i][j]);
        }
        __syncthreads();
    }

    // epilogue
    int t = blockIdx.y;                 // 0=q, 1=k, 2=v
    int hh = tx >> 2;                   // head 0..3 (8 cols/thread, all within one head)
    float4 bb0 = *(const float4*)&bias[cbase + tx * 8];
    float4 bb1 = *(const float4*)&bias[cbase + tx * 8 + 4];
#pragma unroll
    for (int i = 0; i < 8; i++) {
        int n = nbase + ty * 8 + i;
        float4 lo, hi;
        lo.x = acc[i][0] + bb0.x;
        lo.y = acc[i][1] + bb0.y;
        lo.z = acc[i][2] + bb0.z;
        lo.w = acc[i][3] + bb0.w;
        hi.x = acc[i][4] + bb1.x;
        hi.y = acc[i][5] + bb1.y;
        hi.z = acc[i][6] + bb1.z;
        hi.w = acc[i][7] + bb1.w;
        float s = lo.x * lo.x + lo.y * lo.y + lo.z * lo.z + lo.w * lo.w +
                  hi.x * hi.x + hi.y * hi.y + hi.z * hi.z + hi.w * hi.w;
        s += __shfl_xor(s, 1);
        s += __shfl_xor(s, 2);          // sum over the head's 4 tx-lanes (32 channels)
        if (n < Nn) {
            if (t == 0) {
                *(float4*)&qh[(size_t)n * 128 + tx * 8] = lo;
                *(float4*)&qh[(size_t)n * 128 + tx * 8 + 4] = hi;
                if ((tx & 3) == 0) tvec[n * 16 + 8 + hh] = sqrtf(s + 1.0f);
            } else if (t == 1) {
                *(float4*)&kv[(size_t)n * 256 + tx * 8] = lo;
                *(float4*)&kv[(size_t)n * 256 + tx * 8 + 4] = hi;
                if ((tx & 3) == 0) tvec[n * 16 + hh] = sqrtf(s + 1.0f);
            } else {
                *(float4*)&kv[(size_t)n * 256 + 128 + tx * 8] = lo;
                *(float4*)&kv[(size_t)n * 256 + 128 + tx * 8 + 4] = hi;
                if ((tx & 3) == 0) tvec[n * 16 + 4 + hh] = sqrtf(s + 1.0f);
            }
        }
    }
}

__global__ void count_kernel(const int* __restrict__ ei, int* __restrict__ deg, int E) {
    int e = blockIdx.x * blockDim.x + threadIdx.x;
    if (e < E) atomicAdd(&deg[ei[E + e]], 1);
}

// ---- hierarchical exclusive scan (N <= 256*256) ----
__global__ __launch_bounds__(256) void scan_blocks(const int* __restrict__ deg,
                                                   int* __restrict__ offsets,
                                                   int* __restrict__ partials, int n) {
    __shared__ int wsum[4];
    int tid = threadIdx.x;
    int idx = blockIdx.x * 256 + tid;
    int lane = tid & 63, wid = tid >> 6;
    int v = (idx < n) ? deg[idx] : 0;
    int x = v;
#pragma unroll
    for (int d = 1; d < 64; d <<= 1) {
        int y = __shfl_up(x, d, 64);
        if (lane >= d) x += y;
    }
    if (lane == 63) wsum[wid] = x;
    __syncthreads();
    if (tid == 0) {
        int s = 0;
#pragma unroll
        for (int i = 0; i < 4; i++) { int tv = wsum[i]; wsum[i] = s; s += tv; }
    }
    __syncthreads();
    int excl = wsum[wid] + x - v;
    if (idx < n) offsets[idx] = excl;
    if (tid == 255) partials[blockIdx.x] = excl + v;
}

__global__ __launch_bounds__(256) void scan_partials(int* __restrict__ partials,
                                                     int* __restrict__ total_out, int nb) {
    __shared__ int wsum[4];
    int tid = threadIdx.x;
    int lane = tid & 63, wid = tid >> 6;
    int v = (tid < nb) ? partials[tid] : 0;
    int x = v;
#pragma unroll
    for (int d = 1; d < 64; d <<= 1) {
        int y = __shfl_up(x, d, 64);
        if (lane >= d) x += y;
    }
    if (lane == 63) wsum[wid] = x;
    __syncthreads();
    if (tid == 0) {
        int s = 0;
#pragma unroll
        for (int i = 0; i < 4; i++) { int tv = wsum[i]; wsum[i] = s; s += tv; }
    }
    __syncthreads();
    int excl = wsum[wid] + x - v;
    if (tid < nb) partials[tid] = excl;
    if (tid == 255) *total_out = excl + v;
}

__global__ void scan_add(int* __restrict__ offsets, const int* __restrict__ partials, int n) {
    int idx = blockIdx.x * blockDim.x + threadIdx.x;
    if (idx < n) offsets[idx] += partials[blockIdx.x];
}

__global__ void fill_kernel(const int* __restrict__ ei, const int* __restrict__ offsets,
                            int* __restrict__ cursor, int* __restrict__ srcs, int E) {
    int e = blockIdx.x * blockDim.x + threadIdx.x;
    if (e < E) {
        int src = ei[e];
        int dst = ei[E + e];
        int pos = atomicAdd(&cursor[dst], 1);
        srcs[offsets[dst] + pos] = src * 256;   // pre-scaled kv row offset
    }
}

// ---- K3: cooperative-gather attention ----
// Wave = 1 dst node. 4 groups of 16 consecutive lanes, group t handles edges r0+t, r0+t+4, ...
// Per edge: 4 lane-consecutive float4 loads fetch the whole 1KB kv row (8 line transactions).
// Lane l holds k floats {l*4..l*4+3} (head l>>3) and {64+l*4..} (head 2+(l>>3)); dots are
// reduced over 8-lane shfl_xor trees; per-head kt/vt broadcast from the tvec row.
__global__ __launch_bounds__(256) void attn_kernel(const float* __restrict__ qh,
                                                   const float* __restrict__ kv,
                                                   const float* __restrict__ tvec,
                                                   const int* __restrict__ offsets,
                                                   const int* __restrict__ soff,
                                                   float* __restrict__ mid, int Nn) {
    int tid = threadIdx.x;
    int n = (blockIdx.x * blockDim.x + tid) >> 6;   // one node per wave
    if (n >= Nn) return;
    int lw = tid & 63;
    int t = lw >> 4;            // edge-quarter 0..3
    int l = lw & 15;            // lane within group
    int base = lw & 48;         // group's first lane (absolute)
    int ha = l >> 3;            // slot-A head (0/1); slot-B head = 2+ha

    float4 qa = *(const float4*)&qh[(size_t)n * 128 + l * 4];
    float4 qb = *(const float4*)&qh[(size_t)n * 128 + 64 + l * 4];
    float qta = tvec[n * 16 + 8 + ha];
    float qtb = tvec[n * 16 + 10 + ha];

    float4 acc_a = {0.f, 0.f, 0.f, 0.f}, acc_b = {0.f, 0.f, 0.f, 0.f};
    float acc_ta = 0.f, acc_tb = 0.f;

    int r0 = offsets[n], r1 = offsets[n + 1];
    int e = r0 + t;
    int off = (e < r1) ? soff[e] : 0;
    for (; e < r1; e += 4) {
        int offn = (e + 4 < r1) ? soff[e + 4] : 0;   // prefetch next row offset
        const float* row = kv + off;
        float4 k0 = *(const float4*)&row[l * 4];
        float4 k1 = *(const float4*)&row[64 + l * 4];
        float4 v0 = *(const float4*)&row[128 + l * 4];
        float4 v1 = *(const float4*)&row[192 + l * 4];
        float tv = tvec[(off >> 4) + (l & 7)];       // kt[0..3], vt[0..3]

        float pa = qa.x * k0.x + qa.y * k0.y + qa.z * k0.z + qa.w * k0.w;
        float pb = qb.x * k1.x + qb.y * k1.y + qb.z * k1.z + qb.w * k1.w;
        pa += __shfl_xor(pa, 1);
        pb += __shfl_xor(pb, 1);
        pa += __shfl_xor(pa, 2);
        pb += __shfl_xor(pb, 2);
        pa += __shfl_xor(pa, 4);
        pb += __shfl_xor(pb, 4);
        float kta = __shfl(tv, base + ha);
        float ktb = __shfl(tv, base + 2 + ha);
        float vta = __shfl(tv, base + 4 + ha);
        float vtb = __shfl(tv, base + 6 + ha);
        // score = (2 + 2*cinner)/sqrt(32), cinner = <q_s,k_s> - q_t*k_t <= -1 => score <= 0
        float sa = (1.0f + pa - qta * kta) * 0.35355339059327373f;
        float sb = (1.0f + pb - qtb * ktb) * 0.35355339059327373f;
        float wa = __expf(sa), wb = __expf(sb);
        acc_a.x += wa * v0.x; acc_a.y += wa * v0.y; acc_a.z += wa * v0.z; acc_a.w += wa * v0.w;
        acc_b.x += wb * v1.x; acc_b.y += wb * v1.y; acc_b.z += wb * v1.z; acc_b.w += wb * v1.w;
        acc_ta = fmaf(wa, vta, acc_ta);
        acc_tb = fmaf(wb, vtb, acc_tb);
        off = offn;
    }

    // merge the 4 edge-quarters
#define MRG(x) x += __shfl_xor(x, 16); x += __shfl_xor(x, 32);
    MRG(acc_a.x) MRG(acc_a.y) MRG(acc_a.z) MRG(acc_a.w)
    MRG(acc_b.x) MRG(acc_b.y) MRG(acc_b.z) MRG(acc_b.w)
    MRG(acc_ta) MRG(acc_tb)
#undef MRG

    // per-head Lorentz normalization: out = acc / sqrt(clip(|<acc,acc>_L|, 1e-8))
    float ssa = acc_a.x * acc_a.x + acc_a.y * acc_a.y + acc_a.z * acc_a.z + acc_a.w * acc_a.w;
    float ssb = acc_b.x * acc_b.x + acc_b.y * acc_b.y + acc_b.z * acc_b.z + acc_b.w * acc_b.w;
    ssa += __shfl_xor(ssa, 1);
    ssb += __shfl_xor(ssb, 1);
    ssa += __shfl_xor(ssa, 2);
    ssb += __shfl_xor(ssb, 2);
    ssa += __shfl_xor(ssa, 4);
    ssb += __shfl_xor(ssb, 4);
    float ca = ssa - acc_ta * acc_ta;
    float cb = ssb - acc_tb * acc_tb;
    float inva = 1.0f / sqrtf(fmaxf(fabsf(ca), 1e-8f));
    float invb = 1.0f / sqrtf(fmaxf(fabsf(cb), 1e-8f));

    if (t == 0) {
        float4 oa = {acc_a.x * inva, acc_a.y * inva, acc_a.z * inva, acc_a.w * inva};
        float4 ob = {acc_b.x * invb, acc_b.y * invb, acc_b.z * invb, acc_b.w * invb};
        *(float4*)&mid[(size_t)n * 128 + l * 4] = oa;
        *(float4*)&mid[(size_t)n * 128 + 64 + l * 4] = ob;
    }
}

// ---- K4: final hyperbolic linear: 32 nodes/block, 128 threads (one per out-dim) ----
__global__ __launch_bounds__(128) void final_linear(const float* __restrict__ mid,
                                                    const float* __restrict__ WoT,
                                                    const float* __restrict__ bo,
                                                    float* __restrict__ out, int Nn) {
    __shared__ __align__(16) float xl[32][132];
    int tid = threadIdx.x;
    int nb = blockIdx.x * 32;
#pragma unroll
    for (int i = 0; i < 32; i++) {
        int n = nb + i;
        xl[i][1 + tid] = (n < Nn) ? mid[(size_t)n * 128 + tid] : 0.f;
    }
    __syncthreads();
    int nl = tid >> 2, sub = tid & 3;
    {
        float s = 0.f;
#pragma unroll
        for (int j = 0; j < 32; j++) {
            float v = xl[nl][1 + sub * 32 + j];
            s += v * v;
        }
        s += __shfl_xor(s, 1);
        s += __shfl_xor(s, 2);
        if (sub == 0) xl[nl][0] = sqrtf(s + 1.0f);
    }
    __syncthreads();

    float bv = bo[tid];
    float acc[32];
#pragma unroll
    for (int i = 0; i < 32; i++) acc[i] = bv;

    for (int k = 0; k < 128; k += 4) {
        float w0 = WoT[(size_t)(k + 0) * 128 + tid];
        float w1 = WoT[(size_t)(k + 1) * 128 + tid];
        float w2 = WoT[(size_t)(k + 2) * 128 + tid];
        float w3 = WoT[(size_t)(k + 3) * 128 + tid];
#pragma unroll
        for (int i = 0; i < 32; i++) {
            float4 xv = *(const float4*)&xl[i][k];   // broadcast reads
            acc[i] += w0 * xv.x + w1 * xv.y + w2 * xv.z + w3 * xv.w;
        }
    }
    {
        float w = WoT[(size_t)128 * 128 + tid];
#pragma unroll
        for (int i = 0; i < 32; i++) acc[i] += w * xl[i][128];
    }
    __syncthreads();
#pragma unroll
    for (int i = 0; i < 32; i++) {
        int n = nb + i;
        if (n < Nn) out[(size_t)n * 129 + 1 + tid] = acc[i];
        xl[i][tid] = acc[i] * acc[i];
    }
    __syncthreads();
    {
        float s = 0.f;
#pragma unroll
        for (int j = 0; j < 32; j++) s += xl[nl][sub * 32 + j];
        s += __shfl_xor(s, 1);
        s += __shfl_xor(s, 2);
        if (sub == 0 && (nb + nl) < Nn) out[(size_t)(nb + nl) * 129] = sqrtf(s + 1.0f);
    }
}

// legacy single-block scan fallback (only used if N > 65536)
__global__ __launch_bounds__(1024) void scan_kernel(const int* __restrict__ deg,
                                                    int* __restrict__ offsets, int n) {
    __shared__ int wsum[16];
    __shared__ int carry_s;
    int tid = threadIdx.x;
    int lane = tid & 63, wid = tid >> 6;
    if (tid == 0) carry_s = 0;
    __syncthreads();
    for (int base = 0; base < n; base += 1024) {
        int idx = base + tid;
        int v = (idx < n) ? deg[idx] : 0;
        int x = v;
#pragma unroll
        for (int d = 1; d < 64; d <<= 1) {
            int y = __shfl_up(x, d, 64);
            if (lane >= d) x += y;
        }
        if (lane == 63) wsum[wid] = x;
        __syncthreads();
        if (wid == 0) {
            int s = (lane < 16) ? wsum[lane] : 0;
#pragma unroll
            for (int d = 1; d < 16; d <<= 1) {
                int y = __shfl_up(s, d, 64);
                if (lane >= d) s += y;
            }
            if (lane < 16) wsum[lane] = s;
        }
        __syncthreads();
        int waveoff = (wid > 0) ? wsum[wid - 1] : 0;
        int excl = carry_s + waveoff + x - v;
        if (idx < n) offsets[idx] = excl;
        __syncthreads();
        if (tid == 0) carry_s += wsum[15];
        __syncthreads();
    }
    if (tid == 0) offsets[n] = carry_s;
}

extern "C" void kernel_launch(void* const* d_in, const int* in_sizes, int n_in,
                              void* d_out, int out_size, void* d_ws, size_t ws_size,
                              hipStream_t stream) {
    const float* x  = (const float*)d_in[0];
    const int*   ei = (const int*)d_in[1];
    const float* Wq = (const float*)d_in[2];
    const float* bq = (const float*)d_in[3];
    const float* Wk = (const float*)d_in[4];
    const float* bk = (const float*)d_in[5];
    const float* Wv = (const float*)d_in[6];
    const float* bv = (const float*)d_in[7];
    const float* Wo = (const float*)d_in[8];
    const float* bo = (const float*)d_in[9];
    float* out = (float*)d_out;

    const int N = in_sizes[0] / 129;
    const int E = in_sizes[1] / 2;

    // workspace layout (256B-aligned bump allocator)
    char* w = (char*)d_ws;
    size_t off = 0;
    auto alloc = [&](size_t bytes) {
        void* p = w + off;
        off += (bytes + 255) & ~(size_t)255;
        return p;
    };
    float* qh       = (float*)alloc((size_t)N * 128 * 4);
    float* kv       = (float*)alloc((size_t)N * 256 * 4);
    float* tvec     = (float*)alloc((size_t)N * 16 * 4);
    float* mid      = (float*)alloc((size_t)N * 128 * 4);
    float* WT       = (float*)alloc(129 * 384 * 4);
    float* bias     = (float*)alloc(384 * 4);
    float* WoT      = (float*)alloc(129 * 128 * 4);
    int*   offsets  = (int*)alloc((size_t)(N + 1) * 4);
    int*   degcur   = (int*)alloc((size_t)2 * N * 4);  // deg[N] + cursor[N]
    int*   deg      = degcur;
    int*   cursor   = degcur + N;
    int*   partials = (int*)alloc(256 * 4);
    int*   srcs     = (int*)alloc((size_t)E * 4);

    hipMemsetAsync(degcur, 0, (size_t)2 * N * 4, stream);

    prep_kernel<<<260, 256, 0, stream>>>(Wq, bq, Wk, bk, Wv, bv, Wo, WT, bias, WoT);

    dim3 g1((N + 127) / 128, 3);
    qkv_gemm<<<g1, 256, 0, stream>>>(x, WT, bias, qh, kv, tvec, N);

    count_kernel<<<(E + 255) / 256, 256, 0, stream>>>(ei, deg, E);

    int nb = (N + 255) / 256;
    if (nb <= 256) {
        scan_blocks<<<nb, 256, 0, stream>>>(deg, offsets, partials, N);
        scan_partials<<<1, 256, 0, stream>>>(partials, offsets + N, nb);
        scan_add<<<nb, 256, 0, stream>>>(offsets, partials, N);
    } else {
        scan_kernel<<<1, 1024, 0, stream>>>(deg, offsets, N);
    }

    fill_kernel<<<(E + 255) / 256, 256, 0, stream>>>(ei, offsets, cursor, srcs, E);

    attn_kernel<<<(N + 3) / 4, 256, 0, stream>>>(qh, kv, tvec, offsets, srcs, mid, N);

    final_linear<<<(N + 31) / 32, 128, 0, stream>>>(mid, WoT, bo, out, N);
}

// Round 9
// 376.731 us; speedup vs baseline: 2.0901x; 1.2193x over previous
//
#include <hip/hip_runtime.h>
#include <hip/hip_bf16.h>
#include <math.h>

// Problem constants (from reference): D=128, H=4, HD=32, K=1.0
// N = in_sizes[0]/129, E = in_sizes[1]/2.
//
// Pipeline:
//  P0  prep:      WT[129][384] (qkv weights transposed), bias[384], WoT[129][128]
//  P1  xpose:     xT[129][N] = x^T (32x32 LDS tiles) -> vectorizable GEMM staging
//  K1  qkv_gemm:  128x128 tile, 8x8/thread fp32 GEMM from xT. q -> qh[N][128] fp32;
//                 k,v -> kvb[N][256] bf16 (k: 0..127, v: 128..255; RNE pack)
//  K2  count/scan/fill: CSR by dst; srcs pre-scaled by 256 (bf16 kv row stride)
//  K3  attn:      16 lanes/edge cooperative: 2x16B bf16 loads (512B/edge, half of fp32);
//                 qt/kt/vt recomputed in-kernel from quantized vectors (hyperboloid
//                 constraint exact for quantized points; no tvec gather). 3 shfl-tree
//                 dots. Wave = 1 node x 4 edge-quarters. No max subtraction needed
//                 (<q,k>_L <= -1 => score <= 0 => exp in (0,1]); softmax denominator
//                 cancels in the Lorentz normalization.
//  K4  final:     out = hyp_linear(concat(time,space), Wo, bo)

typedef unsigned int uint32;
typedef unsigned short ushort16;

__device__ __forceinline__ float lo16(uint32 u) { return __uint_as_float(u << 16); }
__device__ __forceinline__ float hi16(uint32 u) { return __uint_as_float(u & 0xFFFF0000u); }
__device__ __forceinline__ uint32 f2bf(float f) {   // round-to-nearest-even bf16 bits
    uint32 u = __float_as_uint(f);
    return (u + 0x7FFFu + ((u >> 16) & 1u)) >> 16;
}

__global__ void prep_kernel(const float* __restrict__ Wq, const float* __restrict__ bq,
                            const float* __restrict__ Wk, const float* __restrict__ bk,
                            const float* __restrict__ Wv, const float* __restrict__ bv,
                            const float* __restrict__ Wo,
                            float* __restrict__ WT, float* __restrict__ bias,
                            float* __restrict__ WoT) {
    const int T1 = 129 * 384;
    const int T2 = T1 + 384;
    const int T3 = T2 + 129 * 128;
    for (int i = blockIdx.x * blockDim.x + threadIdx.x; i < T3; i += gridDim.x * blockDim.x) {
        if (i < T1) {
            int k = i / 384, o = i % 384;
            const float* W = (o < 128) ? Wq : (o < 256 ? Wk : Wv);
            int r = o & 127;
            WT[i] = W[(size_t)r * 129 + k];
        } else if (i < T2) {
            int o = i - T1;
            const float* b = (o < 128) ? bq : (o < 256 ? bk : bv);
            bias[o] = b[o & 127];
        } else {
            int j = i - T2;
            int k = j >> 7, o = j & 127;
            WoT[j] = Wo[(size_t)o * 129 + k];
        }
    }
}

// ---- P1: xT[k][n] = x[n][k], 32x32 LDS tiles, both sides coalesced ----
__global__ __launch_bounds__(256) void xpose(const float* __restrict__ x,
                                             float* __restrict__ xT, int Nn) {
    __shared__ float tile[32][33];
    int n0 = blockIdx.x * 32;
    int k0 = blockIdx.y * 32;
    int tx = threadIdx.x & 31, ty = threadIdx.x >> 5;   // ty 0..7
#pragma unroll
    for (int i = 0; i < 4; i++) {
        int nl = ty + i * 8;
        int n = n0 + nl, k = k0 + tx;
        tile[nl][tx] = (n < Nn && k < 129) ? x[(size_t)n * 129 + k] : 0.f;
    }
    __syncthreads();
#pragma unroll
    for (int i = 0; i < 4; i++) {
        int kl = ty + i * 8;
        int k = k0 + kl, n = n0 + tx;
        if (k < 129 && n < Nn) xT[(size_t)k * Nn + n] = tile[tx][kl];
    }
}

// ---- K1: 128-node x 128-channel tile, 8x8/thread, staged from xT (all float4) ----
__global__ __launch_bounds__(256) void qkv_gemm(const float* __restrict__ xT,
                                                const float* __restrict__ WT,
                                                const float* __restrict__ bias,
                                                float* __restrict__ qh,
                                                ushort16* __restrict__ kvb, int Nn) {
    __shared__ __align__(16) float xs[16][132];
    __shared__ __align__(16) float ws[16][132];
    int tid = threadIdx.x;
    int tx = tid & 15, ty = tid >> 4;
    int nbase = blockIdx.x * 128;
    int cbase = blockIdx.y * 128;

    float acc[8][8];
#pragma unroll
    for (int i = 0; i < 8; i++)
#pragma unroll
        for (int j = 0; j < 8; j++) acc[i][j] = 0.f;

    for (int k0 = 0; k0 < 129; k0 += 16) {
        // stage x tile from xT: 16 k-rows x 128 nodes, float4
#pragma unroll
        for (int it = 0; it < 2; it++) {
            int j = tid + it * 256;          // 0..511
            int kk = j >> 5, c4 = j & 31;
            int k = k0 + kk, n0 = nbase + c4 * 4;
            float4 xv = {0.f, 0.f, 0.f, 0.f};
            if (k < 129) {
                if (n0 + 4 <= Nn) {
                    xv = *(const float4*)&xT[(size_t)k * Nn + n0];
                } else {
                    const float* r = &xT[(size_t)k * Nn];
                    if (n0 + 0 < Nn) xv.x = r[n0 + 0];
                    if (n0 + 1 < Nn) xv.y = r[n0 + 1];
                    if (n0 + 2 < Nn) xv.z = r[n0 + 2];
                    if (n0 + 3 < Nn) xv.w = r[n0 + 3];
                }
            }
            *(float4*)&xs[kk][c4 * 4] = xv;
        }
        // stage w tile: 16 k x 128 c, float4
#pragma unroll
        for (int it = 0; it < 2; it++) {
            int i = tid + it * 256;
            int c4 = i & 31, kk = i >> 5;
            int k = k0 + kk;
            float4 wv = {0.f, 0.f, 0.f, 0.f};
            if (k < 129) wv = *(const float4*)&WT[(size_t)k * 384 + cbase + c4 * 4];
            *(float4*)&ws[kk][c4 * 4] = wv;
        }
        __syncthreads();
#pragma unroll
        for (int kk = 0; kk < 16; kk++) {
            float4 a0 = *(const float4*)&xs[kk][ty * 8];
            float4 a1 = *(const float4*)&xs[kk][ty * 8 + 4];
            float4 b0 = *(const float4*)&ws[kk][tx * 8];
            float4 b1 = *(const float4*)&ws[kk][tx * 8 + 4];
            float av[8] = {a0.x, a0.y, a0.z, a0.w, a1.x, a1.y, a1.z, a1.w};
            float bw[8] = {b0.x, b0.y, b0.z, b0.w, b1.x, b1.y, b1.z, b1.w};
#pragma unroll
            for (int i = 0; i < 8; i++)
#pragma unroll
                for (int j = 0; j < 8; j++) acc[i][j] = fmaf(av[i], bw[j], acc[i][j]);
        }
        __syncthreads();
    }

    // epilogue: bias add; q -> fp32, k/v -> bf16 RNE pack (16B per thread-row)
    int t = blockIdx.y;                 // 0=q, 1=k, 2=v
    float4 bb0 = *(const float4*)&bias[cbase + tx * 8];
    float4 bb1 = *(const float4*)&bias[cbase + tx * 8 + 4];
#pragma unroll
    for (int i = 0; i < 8; i++) {
        int n = nbase + ty * 8 + i;
        if (n >= Nn) continue;
        float o[8];
        o[0] = acc[i][0] + bb0.x; o[1] = acc[i][1] + bb0.y;
        o[2] = acc[i][2] + bb0.z; o[3] = acc[i][3] + bb0.w;
        o[4] = acc[i][4] + bb1.x; o[5] = acc[i][5] + bb1.y;
        o[6] = acc[i][6] + bb1.z; o[7] = acc[i][7] + bb1.w;
        if (t == 0) {
            *(float4*)&qh[(size_t)n * 128 + tx * 8] = *(float4*)&o[0];
            *(float4*)&qh[(size_t)n * 128 + tx * 8 + 4] = *(float4*)&o[4];
        } else {
            uint4 p;
            p.x = f2bf(o[0]) | (f2bf(o[1]) << 16);
            p.y = f2bf(o[2]) | (f2bf(o[3]) << 16);
            p.z = f2bf(o[4]) | (f2bf(o[5]) << 16);
            p.w = f2bf(o[6]) | (f2bf(o[7]) << 16);
            int base = (t == 1) ? 0 : 128;
            *(uint4*)&kvb[(size_t)n * 256 + base + tx * 8] = p;
        }
    }
}

__global__ void count_kernel(const int* __restrict__ ei, int* __restrict__ deg, int E) {
    int e = blockIdx.x * blockDim.x + threadIdx.x;
    if (e < E) atomicAdd(&deg[ei[E + e]], 1);
}

// ---- hierarchical exclusive scan (N <= 256*256) ----
__global__ __launch_bounds__(256) void scan_blocks(const int* __restrict__ deg,
                                                   int* __restrict__ offsets,
                                                   int* __restrict__ partials, int n) {
    __shared__ int wsum[4];
    int tid = threadIdx.x;
    int idx = blockIdx.x * 256 + tid;
    int lane = tid & 63, wid = tid >> 6;
    int v = (idx < n) ? deg[idx] : 0;
    int x = v;
#pragma unroll
    for (int d = 1; d < 64; d <<= 1) {
        int y = __shfl_up(x, d, 64);
        if (lane >= d) x += y;
    }
    if (lane == 63) wsum[wid] = x;
    __syncthreads();
    if (tid == 0) {
        int s = 0;
#pragma unroll
        for (int i = 0; i < 4; i++) { int tv = wsum[i]; wsum[i] = s; s += tv; }
    }
    __syncthreads();
    int excl = wsum[wid] + x - v;
    if (idx < n) offsets[idx] = excl;
    if (tid == 255) partials[blockIdx.x] = excl + v;
}

__global__ __launch_bounds__(256) void scan_partials(int* __restrict__ partials,
                                                     int* __restrict__ total_out, int nb) {
    __shared__ int wsum[4];
    int tid = threadIdx.x;
    int lane = tid & 63, wid = tid >> 6;
    int v = (tid < nb) ? partials[tid] : 0;
    int x = v;
#pragma unroll
    for (int d = 1; d < 64; d <<= 1) {
        int y = __shfl_up(x, d, 64);
        if (lane >= d) x += y;
    }
    if (lane == 63) wsum[wid] = x;
    __syncthreads();
    if (tid == 0) {
        int s = 0;
#pragma unroll
        for (int i = 0; i < 4; i++) { int tv = wsum[i]; wsum[i] = s; s += tv; }
    }
    __syncthreads();
    int excl = wsum[wid] + x - v;
    if (tid < nb) partials[tid] = excl;
    if (tid == 255) *total_out = excl + v;
}

__global__ void scan_add(int* __restrict__ offsets, const int* __restrict__ partials, int n) {
    int idx = blockIdx.x * blockDim.x + threadIdx.x;
    if (idx < n) offsets[idx] += partials[blockIdx.x];
}

__global__ void fill_kernel(const int* __restrict__ ei, const int* __restrict__ offsets,
                            int* __restrict__ cursor, int* __restrict__ srcs, int E) {
    int e = blockIdx.x * blockDim.x + threadIdx.x;
    if (e < E) {
        int src = ei[e];
        int dst = ei[E + e];
        int pos = atomicAdd(&cursor[dst], 1);
        srcs[offsets[dst] + pos] = src * 256;   // pre-scaled bf16 kv row offset
    }
}

// ---- K3: cooperative-gather attention, bf16 kv ----
// Wave = 1 dst node, 4 groups of 16 lanes; group t takes edges r0+t, r0+t+4, ...
// Per edge: 2 lane-consecutive 16B loads cover the 512B bf16 kv row. Lane l holds
// elems l*8..l*8+7 of k AND v (head l>>2; 4 lanes per head). q·k, |k|^2, |v|^2 reduced
// via shfl_xor(1,2) within the head's 4 lanes; kt/vt/qt = sqrt(|.|^2+1) recomputed.
__global__ __launch_bounds__(256) void attn_kernel(const float* __restrict__ qh,
                                                   const ushort16* __restrict__ kvb,
                                                   const int* __restrict__ offsets,
                                                   const int* __restrict__ soff,
                                                   float* __restrict__ mid, int Nn) {
    int tid = threadIdx.x;
    int n = (blockIdx.x * blockDim.x + tid) >> 6;   // one node per wave
    if (n >= Nn) return;
    int lw = tid & 63;
    int t = lw >> 4;            // edge-quarter 0..3
    int l = lw & 15;            // lane within group; head = l>>2

    const float* qrow = qh + (size_t)n * 128 + l * 8;
    float4 q0 = *(const float4*)qrow;
    float4 q1 = *(const float4*)(qrow + 4);
    float q2 = q0.x * q0.x + q0.y * q0.y + q0.z * q0.z + q0.w * q0.w +
               q1.x * q1.x + q1.y * q1.y + q1.z * q1.z + q1.w * q1.w;
    q2 += __shfl_xor(q2, 1);
    q2 += __shfl_xor(q2, 2);
    float qt = sqrtf(q2 + 1.0f);

    float acc[8];
#pragma unroll
    for (int i = 0; i < 8; i++) acc[i] = 0.f;
    float acct = 0.f;

    int r0 = offsets[n], r1 = offsets[n + 1];
    int e = r0 + t;
    int off = (e < r1) ? soff[e] : 0;
    for (; e < r1; e += 4) {
        int offn = (e + 4 < r1) ? soff[e + 4] : 0;   // prefetch next row offset
        const ushort16* row = kvb + off;
        uint4 ku = *(const uint4*)(row + l * 8);
        uint4 vu = *(const uint4*)(row + 128 + l * 8);

        float kf[8] = {lo16(ku.x), hi16(ku.x), lo16(ku.y), hi16(ku.y),
                       lo16(ku.z), hi16(ku.z), lo16(ku.w), hi16(ku.w)};
        float vf[8] = {lo16(vu.x), hi16(vu.x), lo16(vu.y), hi16(vu.y),
                       lo16(vu.z), hi16(vu.z), lo16(vu.w), hi16(vu.w)};
        float qf[8] = {q0.x, q0.y, q0.z, q0.w, q1.x, q1.y, q1.z, q1.w};

        float qk = 0.f, k2 = 0.f, v2 = 0.f;
#pragma unroll
        for (int j = 0; j < 8; j++) {
            qk = fmaf(qf[j], kf[j], qk);
            k2 = fmaf(kf[j], kf[j], k2);
            v2 = fmaf(vf[j], vf[j], v2);
        }
        qk += __shfl_xor(qk, 1);
        qk += __shfl_xor(qk, 2);
        k2 += __shfl_xor(k2, 1);
        k2 += __shfl_xor(k2, 2);
        v2 += __shfl_xor(v2, 1);
        v2 += __shfl_xor(v2, 2);
        float kt = sqrtf(k2 + 1.0f);
        float vt = sqrtf(v2 + 1.0f);
        // score = (2 + 2*cinner)/sqrt(32), cinner = <q_s,k_s> - q_t*k_t <= -1 => score <= 0
        float s = (1.0f + qk - qt * kt) * 0.35355339059327373f;
        float w = __expf(s);
#pragma unroll
        for (int j = 0; j < 8; j++) acc[j] = fmaf(w, vf[j], acc[j]);
        acct = fmaf(w, vt, acct);
        off = offn;
    }

    // merge the 4 edge-quarters (lane bits 4,5); acct stays per-lane (redundant x4)
#pragma unroll
    for (int j = 0; j < 8; j++) {
        acc[j] += __shfl_xor(acc[j], 16);
        acc[j] += __shfl_xor(acc[j], 32);
    }
    acct += __shfl_xor(acct, 16);
    acct += __shfl_xor(acct, 32);

    // per-head Lorentz normalization: out = acc / sqrt(clip(|<acc,acc>_L|, 1e-8))
    float ss = 0.f;
#pragma unroll
    for (int j = 0; j < 8; j++) ss = fmaf(acc[j], acc[j], ss);
    ss += __shfl_xor(ss, 1);
    ss += __shfl_xor(ss, 2);
    float c = ss - acct * acct;
    float inv = 1.0f / sqrtf(fmaxf(fabsf(c), 1e-8f));

    if (t == 0) {
        float4 o0 = {acc[0] * inv, acc[1] * inv, acc[2] * inv, acc[3] * inv};
        float4 o1 = {acc[4] * inv, acc[5] * inv, acc[6] * inv, acc[7] * inv};
        *(float4*)&mid[(size_t)n * 128 + l * 8] = o0;
        *(float4*)&mid[(size_t)n * 128 + l * 8 + 4] = o1;
    }
}

// ---- K4: final hyperbolic linear: 32 nodes/block, 128 threads (one per out-dim) ----
__global__ __launch_bounds__(128) void final_linear(const float* __restrict__ mid,
                                                    const float* __restrict__ WoT,
                                                    const float* __restrict__ bo,
                                                    float* __restrict__ out, int Nn) {
    __shared__ __align__(16) float xl[32][132];
    int tid = threadIdx.x;
    int nb = blockIdx.x * 32;
#pragma unroll
    for (int i = 0; i < 32; i++) {
        int n = nb + i;
        xl[i][1 + tid] = (n < Nn) ? mid[(size_t)n * 128 + tid] : 0.f;
    }
    __syncthreads();
    int nl = tid >> 2, sub = tid & 3;
    {
        float s = 0.f;
#pragma unroll
        for (int j = 0; j < 32; j++) {
            float v = xl[nl][1 + sub * 32 + j];
            s += v * v;
        }
        s += __shfl_xor(s, 1);
        s += __shfl_xor(s, 2);
        if (sub == 0) xl[nl][0] = sqrtf(s + 1.0f);
    }
    __syncthreads();

    float bv = bo[tid];
    float acc[32];
#pragma unroll
    for (int i = 0; i < 32; i++) acc[i] = bv;

    for (int k = 0; k < 128; k += 4) {
        float w0 = WoT[(size_t)(k + 0) * 128 + tid];
        float w1 = WoT[(size_t)(k + 1) * 128 + tid];
        float w2 = WoT[(size_t)(k + 2) * 128 + tid];
        float w3 = WoT[(size_t)(k + 3) * 128 + tid];
#pragma unroll
        for (int i = 0; i < 32; i++) {
            float4 xv = *(const float4*)&xl[i][k];   // broadcast reads
            acc[i] += w0 * xv.x + w1 * xv.y + w2 * xv.z + w3 * xv.w;
        }
    }
    {
        float w = WoT[(size_t)128 * 128 + tid];
#pragma unroll
        for (int i = 0; i < 32; i++) acc[i] += w * xl[i][128];
    }
    __syncthreads();
#pragma unroll
    for (int i = 0; i < 32; i++) {
        int n = nb + i;
        if (n < Nn) out[(size_t)n * 129 + 1 + tid] = acc[i];
        xl[i][tid] = acc[i] * acc[i];
    }
    __syncthreads();
    {
        float s = 0.f;
#pragma unroll
        for (int j = 0; j < 32; j++) s += xl[nl][sub * 32 + j];
        s += __shfl_xor(s, 1);
        s += __shfl_xor(s, 2);
        if (sub == 0 && (nb + nl) < Nn) out[(size_t)(nb + nl) * 129] = sqrtf(s + 1.0f);
    }
}

// legacy single-block scan fallback (only used if N > 65536)
__global__ __launch_bounds__(1024) void scan_kernel(const int* __restrict__ deg,
                                                    int* __restrict__ offsets, int n) {
    __shared__ int wsum[16];
    __shared__ int carry_s;
    int tid = threadIdx.x;
    int lane = tid & 63, wid = tid >> 6;
    if (tid == 0) carry_s = 0;
    __syncthreads();
    for (int base = 0; base < n; base += 1024) {
        int idx = base + tid;
        int v = (idx < n) ? deg[idx] : 0;
        int x = v;
#pragma unroll
        for (int d = 1; d < 64; d <<= 1) {
            int y = __shfl_up(x, d, 64);
            if (lane >= d) x += y;
        }
        if (lane == 63) wsum[wid] = x;
        __syncthreads();
        if (wid == 0) {
            int s = (lane < 16) ? wsum[lane] : 0;
#pragma unroll
            for (int d = 1; d < 16; d <<= 1) {
                int y = __shfl_up(s, d, 64);
                if (lane >= d) s += y;
            }
            if (lane < 16) wsum[lane] = s;
        }
        __syncthreads();
        int waveoff = (wid > 0) ? wsum[wid - 1] : 0;
        int excl = carry_s + waveoff + x - v;
        if (idx < n) offsets[idx] = excl;
        __syncthreads();
        if (tid == 0) carry_s += wsum[15];
        __syncthreads();
    }
    if (tid == 0) offsets[n] = carry_s;
}

extern "C" void kernel_launch(void* const* d_in, const int* in_sizes, int n_in,
                              void* d_out, int out_size, void* d_ws, size_t ws_size,
                              hipStream_t stream) {
    const float* x  = (const float*)d_in[0];
    const int*   ei = (const int*)d_in[1];
    const float* Wq = (const float*)d_in[2];
    const float* bq = (const float*)d_in[3];
    const float* Wk = (const float*)d_in[4];
    const float* bk = (const float*)d_in[5];
    const float* Wv = (const float*)d_in[6];
    const float* bv = (const float*)d_in[7];
    const float* Wo = (const float*)d_in[8];
    const float* bo = (const float*)d_in[9];
    float* out = (float*)d_out;

    const int N = in_sizes[0] / 129;
    const int E = in_sizes[1] / 2;

    // workspace layout (256B-aligned bump allocator)
    char* w = (char*)d_ws;
    size_t off = 0;
    auto alloc = [&](size_t bytes) {
        void* p = w + off;
        off += (bytes + 255) & ~(size_t)255;
        return p;
    };
    float*    qh       = (float*)alloc((size_t)N * 128 * 4);
    ushort16* kvb      = (ushort16*)alloc((size_t)N * 256 * 2);   // bf16 k|v rows
    float*    xT       = (float*)alloc((size_t)129 * N * 4);
    float*    mid      = (float*)alloc((size_t)N * 128 * 4);
    float*    WT       = (float*)alloc(129 * 384 * 4);
    float*    bias     = (float*)alloc(384 * 4);
    float*    WoT      = (float*)alloc(129 * 128 * 4);
    int*      offsets  = (int*)alloc((size_t)(N + 1) * 4);
    int*      degcur   = (int*)alloc((size_t)2 * N * 4);  // deg[N] + cursor[N]
    int*      deg      = degcur;
    int*      cursor   = degcur + N;
    int*      partials = (int*)alloc(256 * 4);
    int*      srcs     = (int*)alloc((size_t)E * 4);

    hipMemsetAsync(degcur, 0, (size_t)2 * N * 4, stream);

    prep_kernel<<<260, 256, 0, stream>>>(Wq, bq, Wk, bk, Wv, bv, Wo, WT, bias, WoT);

    dim3 gt((N + 31) / 32, 5);
    xpose<<<gt, 256, 0, stream>>>(x, xT, N);

    dim3 g1((N + 127) / 128, 3);
    qkv_gemm<<<g1, 256, 0, stream>>>(xT, WT, bias, qh, kvb, N);

    count_kernel<<<(E + 255) / 256, 256, 0, stream>>>(ei, deg, E);

    int nb = (N + 255) / 256;
    if (nb <= 256) {
        scan_blocks<<<nb, 256, 0, stream>>>(deg, offsets, partials, N);
        scan_partials<<<1, 256, 0, stream>>>(partials, offsets + N, nb);
        scan_add<<<nb, 256, 0, stream>>>(offsets, partials, N);
    } else {
        scan_kernel<<<1, 1024, 0, stream>>>(deg, offsets, N);
    }

    fill_kernel<<<(E + 255) / 256, 256, 0, stream>>>(ei, offsets, cursor, srcs, E);

    attn_kernel<<<(N + 3) / 4, 256, 0, stream>>>(qh, kvb, offsets, srcs, mid, N);

    final_linear<<<(N + 31) / 32, 128, 0, stream>>>(mid, WoT, bo, out, N);
}